// Round 7
// baseline (69.924 us; speedup 1.0000x reference)
//
#include <hip/hip_runtime.h>

typedef unsigned short UST;
typedef __attribute__((ext_vector_type(8))) __bf16 bf16x8;
typedef __attribute__((ext_vector_type(4))) float f32x4;
typedef __attribute__((ext_vector_type(16))) float f32x16;

#define NB 4
#define NH 8
#define LSEQ 1024
#define DMODEL 512
#define DH 64

__device__ __forceinline__ UST f2bf(float f) {
  union { float f; unsigned u; } v; v.f = f;
  unsigned u = v.u;
  return (UST)((u + 0x7FFFu + ((u >> 16) & 1u)) >> 16);
}
__device__ __forceinline__ float bf2f(UST h) {
  union { unsigned u; float f; } v; v.u = ((unsigned)h) << 16;
  return v.f;
}

// ---------------- kernel 1: x (fp32) -> bf16 ----------------
__global__ void k_convert_x(const float* __restrict__ x, UST* __restrict__ xbf) {
  int i = blockIdx.x * 256 + threadIdx.x;   // 2097152/4 elements
  float4 v = ((const float4*)x)[i];
  ushort4 o;
  o.x = f2bf(v.x); o.y = f2bf(v.y); o.z = f2bf(v.z); o.w = f2bf(v.w);
  ((ushort4*)xbf)[i] = o;
}

// ---------------- kernel 2: W [512][1536] fp32 -> WT [1536][512] bf16 ----------------
__global__ void k_transpose_W(const float* __restrict__ W, UST* __restrict__ WT) {
  __shared__ float tile[64][65];
  int n0 = blockIdx.x * 64;   // over 1536
  int k0 = blockIdx.y * 64;   // over 512
  int tx = threadIdx.x & 63, ty = threadIdx.x >> 6;  // ty 0..3
#pragma unroll
  for (int i = 0; i < 16; ++i) {
    int k = ty + i * 4;
    tile[k][tx] = W[(size_t)(k0 + k) * 1536 + n0 + tx];
  }
  __syncthreads();
#pragma unroll
  for (int i = 0; i < 16; ++i) {
    int n = ty + i * 4;
    WT[(size_t)(n0 + n) * 512 + k0 + tx] = f2bf(tile[tx][n]);
  }
}

// ---------------- kernel 3: projection GEMM + scatter (LDS reg-staged pipeline) ----
// q columns are pre-scaled by 0.125 (=1/sqrt(d_head)); alpha inherits the scale
// linearly in k_relpos, so attention scores come out of MFMA already scaled.
__global__ __launch_bounds__(256) void k_proj(
    const UST* __restrict__ xbf, const UST* __restrict__ WT, const float* __restrict__ bias,
    UST* __restrict__ qext, UST* __restrict__ kext, UST* __restrict__ vT) {
  int m0 = blockIdx.x * 128;  // token tile
  int n0 = blockIdx.y * 64;   // out-col tile
  int t = threadIdx.x;
  int lane = t & 63, w = t >> 6;
  int wr = w >> 1, wc = w & 1;
  int g = lane >> 4, c16 = lane & 15;

  __shared__ UST AtS[128 * 64];  // 16KB; (row, slot s) holds global (row, s^(row&7)) [16B units]
  __shared__ UST BtS[64 * 64];   // 8KB; same swizzle

  const char* Ag = (const char*)(xbf + (size_t)m0 * 512);  // row stride 1024B
  const char* Bg = (const char*)(WT + (size_t)n0 * 512);   // row stride 1024B

  bf16x8 areg[4], breg[2];
#pragma unroll
  for (int c = 0; c < 4; ++c) {
    int u = c * 256 + t, r = u >> 3, s = u & 7;
    areg[c] = *(const bf16x8*)(Ag + (size_t)r * 1024 + s * 16);
  }
#pragma unroll
  for (int c = 0; c < 2; ++c) {
    int u = c * 256 + t, r = u >> 3, s = u & 7;
    breg[c] = *(const bf16x8*)(Bg + (size_t)r * 1024 + s * 16);
  }

  f32x4 acc[4][2] = {};
  for (int kk = 0; kk < 512; kk += 64) {
    __syncthreads();
#pragma unroll
    for (int c = 0; c < 4; ++c) {
      int u = c * 256 + t, r = u >> 3, s = u & 7;
      *(bf16x8*)((char*)AtS + (size_t)r * 128 + (s ^ (r & 7)) * 16) = areg[c];
    }
#pragma unroll
    for (int c = 0; c < 2; ++c) {
      int u = c * 256 + t, r = u >> 3, s = u & 7;
      *(bf16x8*)((char*)BtS + (size_t)r * 128 + (s ^ (r & 7)) * 16) = breg[c];
    }
    __syncthreads();

    if (kk + 64 < 512) {
      size_t cb = (size_t)(kk + 64) * 2;
#pragma unroll
      for (int c = 0; c < 4; ++c) {
        int u = c * 256 + t, r = u >> 3, s = u & 7;
        areg[c] = *(const bf16x8*)(Ag + (size_t)r * 1024 + cb + s * 16);
      }
#pragma unroll
      for (int c = 0; c < 2; ++c) {
        int u = c * 256 + t, r = u >> 3, s = u & 7;
        breg[c] = *(const bf16x8*)(Bg + (size_t)r * 1024 + cb + s * 16);
      }
    }

#pragma unroll
    for (int kf = 0; kf < 2; ++kf) {
      bf16x8 af[4], bfr[2];
#pragma unroll
      for (int rf = 0; rf < 4; ++rf) {
        int r = wr * 64 + rf * 16 + c16;
        int s = (kf * 4 + g) ^ (r & 7);
        af[rf] = *(const bf16x8*)((const char*)AtS + (size_t)r * 128 + s * 16);
      }
#pragma unroll
      for (int cf = 0; cf < 2; ++cf) {
        int r = wc * 32 + cf * 16 + c16;
        int s = (kf * 4 + g) ^ (r & 7);
        bfr[cf] = *(const bf16x8*)((const char*)BtS + (size_t)r * 128 + s * 16);
      }
      __builtin_amdgcn_s_setprio(1);
#pragma unroll
      for (int rf = 0; rf < 4; ++rf)
#pragma unroll
        for (int cf = 0; cf < 2; ++cf)
          acc[rf][cf] = __builtin_amdgcn_mfma_f32_16x16x32_bf16(af[rf], bfr[cf], acc[rf][cf], 0, 0, 0);
      __builtin_amdgcn_s_setprio(0);
    }
  }

#pragma unroll
  for (int rf = 0; rf < 4; ++rf) {
#pragma unroll
    for (int cf = 0; cf < 2; ++cf) {
      int c = n0 + wc * 32 + cf * 16 + c16;
      int h = c / 192, rem = c % 192;
      float bv = bias[c];
#pragma unroll
      for (int r = 0; r < 4; ++r) {
        int row = m0 + wr * 64 + rf * 16 + g * 4 + r;
        int bidx = row >> 10, ltok = row & 1023;
        int bh = bidx * 8 + h;
        float val = acc[rf][cf][r] + bv;
        if (rem < 64)
          qext[((size_t)bh * 1024 + ltok) * 128 + rem] = f2bf(val * 0.125f);
        else if (rem < 128)
          kext[((size_t)bh * 1024 + ltok) * 128 + (rem - 64)] = f2bf(val);
        else
          vT[((size_t)bh * 64 + (rem - 128)) * 1024 + ltok] = f2bf(val);
      }
    }
  }
}

// ---------------- kernel 4: relative-position features (alpha/beta) ----------------
__global__ void k_relpos(UST* __restrict__ qext, UST* __restrict__ kext) {
  int gid = blockIdx.x * 256 + threadIdx.x;  // 32*1024*32
  int j = gid & 31;
  int l = (gid >> 5) & 1023;
  int bh = gid >> 15;
  // div_term = exp(-2j*ln(10000)/64) = 2^(-2j*log2(10000)/64), fp32 (matches jnp)
  float dd = exp2f((float)(-2 * j) * 0.20762050593046f);
  float ang = (float)l * dd;
  float s = __sinf(ang), c = __cosf(ang);
  UST* qp = qext + ((size_t)bh * 1024 + l) * 128;
  float qs = bf2f(qp[j]), qc = bf2f(qp[32 + j]);   // already scaled by 0.125
  qp[64 + j] = f2bf(qs * s + qc * c);
  qp[96 + j] = f2bf(qc * s - qs * c);
  UST* kp = kext + ((size_t)bh * 1024 + l) * 128;
  kp[64 + j] = f2bf(c);
  kp[96 + j] = f2bf(s);
}

// ---------------- kernel 5: fused flash attention, 32x32x16 MFMA ----------------
// 4 waves as (wq, wk): QK^T computes S quadrant [wq*32..+32][wk*32..+32] over
// K=128 (8 mfma_32x32x16). P = exp(S) -> swizzled LDS tile Ps[64][64]. PV
// computes O^T quadrant [wk(=wd)*32..+32][wq*32..+32] = sum_k V^T-frag * P-frag
// (4 mfma). Row-sums accumulate per-reg in registers; epilogue shuffle-reduce +
// Ls cross-wk combine. No online max (scores bounded; exp can't overflow fp32).
// Staging identical to verified reg-staged pattern. 3 barriers/iter.
template<int SPLITS>
__global__ __launch_bounds__(256) void k_attn_split(
    const UST* __restrict__ qext, const UST* __restrict__ kext,
    const UST* __restrict__ vT, float* __restrict__ out,
    float* __restrict__ Opart, float* __restrict__ ml) {
  int blk = ((blockIdx.x & 7) << 6) | (blockIdx.x >> 3);  // XCD-contiguous bh ranges
  int split = blockIdx.y;
  int qt = blk & 15, bh = blk >> 4;
  int b = bh >> 3, h = bh & 7;
  int q0 = qt * 64;
  int t = threadIdx.x;
  int lane = t & 63, w = t >> 6;
  int l31 = lane & 31, lh = lane >> 5;
  int wq = w >> 1, wk = w & 1;   // wk doubles as wd (d-half) in the PV phase

  __shared__ UST KtS[64 * 128];    // 16KB; (row, slot s) holds global (row, s^(row&7)) [16B units]
  __shared__ UST VtS[64 * 64];     // 8KB;  [d][k], same swizzle on 128B rows
  __shared__ UST Ps[64 * 64];      // 8KB;  [q][k], same swizzle
  __shared__ float Ls[2][32][2];   // row-sum cross-wk combine

  // Q fragments: A[m=l31][k=kc*16+lh*8+e], rows wq*32+l31
  const UST* qbase = qext + ((size_t)bh * 1024 + q0 + wq * 32 + l31) * 128 + lh * 8;
  bf16x8 qf[8];
#pragma unroll
  for (int kc = 0; kc < 8; ++kc) qf[kc] = *(const bf16x8*)&qbase[kc * 16];

  const char* kgbase = (const char*)(kext + (size_t)bh * 1024 * 128);
  const char* vgbase = (const char*)(vT + (size_t)bh * 64 * 1024);

  f32x16 O = {};
  float l_acc[16] = {};

  int kbeg = split * (LSEQ / SPLITS);
  int kend = kbeg + LSEQ / SPLITS;

  bf16x8 kreg[4], vreg[2];
  {
    const char* kg = kgbase + (size_t)kbeg * 256;
#pragma unroll
    for (int c = 0; c < 4; ++c) {
      int u = c * 256 + t;
      kreg[c] = *(const bf16x8*)(kg + (size_t)(u >> 4) * 256 + (u & 15) * 16);
    }
    const char* vg = vgbase + (size_t)kbeg * 2;
#pragma unroll
    for (int c = 0; c < 2; ++c) {
      int u = c * 256 + t;
      vreg[c] = *(const bf16x8*)(vg + (size_t)(u >> 3) * 2048 + (u & 7) * 16);
    }
  }

  int krow = wk * 32 + l31;   // K-tile row this lane reads in QK (invariant)
  int kcol = wk * 32 + l31;   // S column this lane owns (invariant)
  int drow = wk * 32 + l31;   // V^T row in PV
  int prow = wq * 32 + l31;   // P row in PV

  for (int k0 = kbeg; k0 < kend; k0 += 64) {
    __syncthreads();   // B1: previous tile fully consumed
#pragma unroll
    for (int c = 0; c < 4; ++c) {
      int u = c * 256 + t, r = u >> 4, s = u & 15;
      *(bf16x8*)((char*)KtS + (size_t)r * 256 + (s ^ (r & 7)) * 16) = kreg[c];
    }
#pragma unroll
    for (int c = 0; c < 2; ++c) {
      int u = c * 256 + t, r = u >> 3, s = u & 7;
      *(bf16x8*)((char*)VtS + (size_t)r * 128 + (s ^ (r & 7)) * 16) = vreg[c];
    }
    __syncthreads();   // B2: tile visible

    if (k0 + 64 < kend) {   // prefetch next tile; latency hides under compute
      const char* kg = kgbase + (size_t)(k0 + 64) * 256;
#pragma unroll
      for (int c = 0; c < 4; ++c) {
        int u = c * 256 + t;
        kreg[c] = *(const bf16x8*)(kg + (size_t)(u >> 4) * 256 + (u & 15) * 16);
      }
      const char* vg = vgbase + (size_t)(k0 + 64) * 2;
#pragma unroll
      for (int c = 0; c < 2; ++c) {
        int u = c * 256 + t;
        vreg[c] = *(const bf16x8*)(vg + (size_t)(u >> 3) * 2048 + (u & 7) * 16);
      }
    }

    // ---- S quadrant = Q(32x128) * Kext^T slice (8 x mfma_32x32x16)
    f32x16 sa = {};
#pragma unroll
    for (int kh = 0; kh < 2; ++kh) {
      bf16x8 kfr[4];
#pragma unroll
      for (int kc = 0; kc < 4; ++kc) {
        int slot = ((kh * 4 + kc) * 2 + lh) ^ (krow & 7);
        kfr[kc] = *(const bf16x8*)((const char*)KtS + (size_t)krow * 256 + slot * 16);
      }
      __builtin_amdgcn_s_setprio(1);
#pragma unroll
      for (int kc = 0; kc < 4; ++kc)
        sa = __builtin_amdgcn_mfma_f32_32x32x16_bf16(qf[kh * 4 + kc], kfr[kc], sa, 0, 0, 0);
      __builtin_amdgcn_s_setprio(0);
    }

    // ---- P = exp(S): accumulate row sums, store to swizzled Ps[q][k]
#pragma unroll
    for (int i = 0; i < 16; ++i) {
      float p = __expf(sa[i]);
      l_acc[i] += p;
      int qrow = wq * 32 + (i & 3) + 8 * (i >> 2) + 4 * lh;
      *(UST*)((char*)Ps + (size_t)qrow * 128 + (((kcol >> 3) ^ (qrow & 7)) * 16) + (kcol & 7) * 2) = f2bf(p);
    }
    __syncthreads();   // B3: P visible

    // ---- O^T quadrant += V^T-frag * P-frag (4 x mfma_32x32x16)
    {
      bf16x8 vf[4], pf[4];
#pragma unroll
      for (int kc = 0; kc < 4; ++kc) {
        int sv = (kc * 2 + lh) ^ (drow & 7);
        int sp = (kc * 2 + lh) ^ (prow & 7);
        vf[kc] = *(const bf16x8*)((const char*)VtS + (size_t)drow * 128 + sv * 16);
        pf[kc] = *(const bf16x8*)((const char*)Ps + (size_t)prow * 128 + sp * 16);
      }
      __builtin_amdgcn_s_setprio(1);
#pragma unroll
      for (int kc = 0; kc < 4; ++kc)
        O = __builtin_amdgcn_mfma_f32_32x32x16_bf16(vf[kc], pf[kc], O, 0, 0, 0);
      __builtin_amdgcn_s_setprio(0);
    }
  }

  // ---- epilogue: reduce row sums over the 32 lanes sharing each row
#pragma unroll
  for (int m = 1; m < 32; m <<= 1)
#pragma unroll
    for (int i = 0; i < 16; ++i) l_acc[i] += __shfl_xor(l_acc[i], m, 64);
  if (l31 == 0) {
#pragma unroll
    for (int i = 0; i < 16; ++i)
      Ls[wq][(i & 3) + 8 * (i >> 2) + 4 * lh][wk] = l_acc[i];
  }
  __syncthreads();
  float lsum = Ls[wq][l31][0] + Ls[wq][l31][1];

  int qrow = q0 + wq * 32 + l31;   // this lane's q (O^T column)
  if (SPLITS == 1) {
    float inv = 1.0f / lsum;
    float* op = out + ((size_t)b * 1024 + qrow) * 512 + h * 64 + wk * 32;
#pragma unroll
    for (int grp = 0; grp < 4; ++grp) {
      float4 v = {O[grp * 4 + 0] * inv, O[grp * 4 + 1] * inv,
                  O[grp * 4 + 2] * inv, O[grp * 4 + 3] * inv};
      *(float4*)&op[grp * 8 + lh * 4] = v;
    }
  } else {
    float* op = Opart + (((size_t)split * 32 + bh) * 1024 + qrow) * 64 + wk * 32;
#pragma unroll
    for (int grp = 0; grp < 4; ++grp) {
      float4 v = {O[grp * 4 + 0], O[grp * 4 + 1], O[grp * 4 + 2], O[grp * 4 + 3]};
      *(float4*)&op[grp * 8 + lh * 4] = v;
    }
    if (wk == 0 && lh == 0) {
      float* mp = ml + (((size_t)split * 32 + bh) * 1024 + qrow) * 2;
      mp[0] = 0.f;
      mp[1] = lsum;
    }
  }
}

// ---------------- kernel 6: combine K-splits (no max rebase needed) ----------------
template<int SPLITS>
__global__ void k_combine(const float* __restrict__ Opart, const float* __restrict__ ml,
                          float* __restrict__ out) {
  int gid = blockIdx.x * 256 + threadIdx.x;   // 32*1024*16 threads, 4 floats each
  int dq = (gid & 15) * 4;
  int row = (gid >> 4) & 1023;
  int bh = gid >> 14;
  int b = bh >> 3, h = bh & 7;

  float denom = 0.f;
  float4 acc = {0.f, 0.f, 0.f, 0.f};
#pragma unroll
  for (int s = 0; s < SPLITS; ++s) {
    denom += ml[(((size_t)s * 32 + bh) * 1024 + row) * 2 + 1];
    float4 ov = *(const float4*)&Opart[(((size_t)s * 32 + bh) * 1024 + row) * 64 + dq];
    acc.x += ov.x; acc.y += ov.y; acc.z += ov.z; acc.w += ov.w;
  }
  float inv = 1.0f / denom;
  float4 o = {acc.x * inv, acc.y * inv, acc.z * inv, acc.w * inv};
  *(float4*)&out[((size_t)b * 1024 + row) * 512 + h * 64 + dq] = o;
}

extern "C" void kernel_launch(void* const* d_in, const int* in_sizes, int n_in,
                              void* d_out, int out_size, void* d_ws, size_t ws_size,
                              hipStream_t stream) {
  const float* x = (const float*)d_in[0];
  const float* W = (const float*)d_in[1];
  const float* bias = (const float*)d_in[2];
  float* out = (float*)d_out;

  UST* ws = (UST*)d_ws;
  UST* xbf  = ws;                       // 4096*512
  UST* WT   = xbf + 4096 * 512;         // 1536*512
  UST* qext = WT + 1536 * 512;          // 32*1024*128
  UST* kext = qext + 32 * 1024 * 128;   // 32*1024*128
  UST* vT   = kext + 32 * 1024 * 128;   // 32*64*1024
  UST* bf_end = vT + 32 * 64 * 1024;    // 13,369,344 USTs = 26.7 MB

  size_t base_bytes = (size_t)(bf_end - ws) * sizeof(UST);
  size_t per_split = (size_t)32 * 1024 * 66 * sizeof(float);  // O(64) + m,l per row
  int S = 1;
  if (ws_size >= base_bytes + 2 * per_split) S = 2;

  float* Opart = (float*)bf_end;
  float* ml = Opart + (size_t)S * 32 * 1024 * 64;

  k_convert_x<<<dim3(2048), dim3(256), 0, stream>>>(x, xbf);
  k_transpose_W<<<dim3(24, 8), dim3(256), 0, stream>>>(W, WT);
  k_proj<<<dim3(32, 24), dim3(256), 0, stream>>>(xbf, WT, bias, qext, kext, vT);
  k_relpos<<<dim3(4096), dim3(256), 0, stream>>>(qext, kext);

  if (S == 2) {
    k_attn_split<2><<<dim3(512, 2), dim3(256), 0, stream>>>(qext, kext, vT, out, Opart, ml);
    k_combine<2><<<dim3(2048), dim3(256), 0, stream>>>(Opart, ml, out);
  } else {
    k_attn_split<1><<<dim3(512, 1), dim3(256), 0, stream>>>(qext, kext, vT, out, Opart, ml);
  }
}

// Round 8
// 67.535 us; speedup vs baseline: 1.0354x; 1.0354x over previous
//
#include <hip/hip_runtime.h>

typedef unsigned short UST;
typedef __attribute__((ext_vector_type(8))) __bf16 bf16x8;
typedef __attribute__((ext_vector_type(4))) float f32x4;
typedef __attribute__((ext_vector_type(16))) float f32x16;

#define NB 4
#define NH 8
#define LSEQ 1024
#define DMODEL 512
#define DH 64

__device__ __forceinline__ UST f2bf(float f) {
  union { float f; unsigned u; } v; v.f = f;
  unsigned u = v.u;
  return (UST)((u + 0x7FFFu + ((u >> 16) & 1u)) >> 16);
}
__device__ __forceinline__ float bf2f(UST h) {
  union { unsigned u; float f; } v; v.u = ((unsigned)h) << 16;
  return v.f;
}
__device__ __forceinline__ unsigned cvt_pk_bf16(float lo, float hi) {
  unsigned r;
  asm volatile("v_cvt_pk_bf16_f32 %0, %1, %2" : "=v"(r) : "v"(lo), "v"(hi));
  return r;
}

// ---------------- kernel 1: x (fp32) -> bf16 ----------------
__global__ void k_convert_x(const float* __restrict__ x, UST* __restrict__ xbf) {
  int i = blockIdx.x * 256 + threadIdx.x;   // 2097152/4 elements
  float4 v = ((const float4*)x)[i];
  ushort4 o;
  o.x = f2bf(v.x); o.y = f2bf(v.y); o.z = f2bf(v.z); o.w = f2bf(v.w);
  ((ushort4*)xbf)[i] = o;
}

// ---------------- kernel 2: W [512][1536] fp32 -> WT [1536][512] bf16 ----------------
__global__ void k_transpose_W(const float* __restrict__ W, UST* __restrict__ WT) {
  __shared__ float tile[64][65];
  int n0 = blockIdx.x * 64;   // over 1536
  int k0 = blockIdx.y * 64;   // over 512
  int tx = threadIdx.x & 63, ty = threadIdx.x >> 6;  // ty 0..3
#pragma unroll
  for (int i = 0; i < 16; ++i) {
    int k = ty + i * 4;
    tile[k][tx] = W[(size_t)(k0 + k) * 1536 + n0 + tx];
  }
  __syncthreads();
#pragma unroll
  for (int i = 0; i < 16; ++i) {
    int n = ty + i * 4;
    WT[(size_t)(n0 + n) * 512 + k0 + tx] = f2bf(tile[tx][n]);
  }
}

// ---------------- kernel 3: projection GEMM + scatter (LDS reg-staged pipeline) ----
// q columns are pre-scaled by 0.125 (=1/sqrt(d_head)); alpha inherits the scale
// linearly in k_relpos, so attention scores come out of MFMA already scaled.
__global__ __launch_bounds__(256) void k_proj(
    const UST* __restrict__ xbf, const UST* __restrict__ WT, const float* __restrict__ bias,
    UST* __restrict__ qext, UST* __restrict__ kext, UST* __restrict__ vT) {
  int m0 = blockIdx.x * 128;  // token tile
  int n0 = blockIdx.y * 64;   // out-col tile
  int t = threadIdx.x;
  int lane = t & 63, w = t >> 6;
  int wr = w >> 1, wc = w & 1;
  int g = lane >> 4, c16 = lane & 15;

  __shared__ UST AtS[128 * 64];  // 16KB; (row, slot s) holds global (row, s^(row&7)) [16B units]
  __shared__ UST BtS[64 * 64];   // 8KB; same swizzle

  const char* Ag = (const char*)(xbf + (size_t)m0 * 512);  // row stride 1024B
  const char* Bg = (const char*)(WT + (size_t)n0 * 512);   // row stride 1024B

  bf16x8 areg[4], breg[2];
#pragma unroll
  for (int c = 0; c < 4; ++c) {
    int u = c * 256 + t, r = u >> 3, s = u & 7;
    areg[c] = *(const bf16x8*)(Ag + (size_t)r * 1024 + s * 16);
  }
#pragma unroll
  for (int c = 0; c < 2; ++c) {
    int u = c * 256 + t, r = u >> 3, s = u & 7;
    breg[c] = *(const bf16x8*)(Bg + (size_t)r * 1024 + s * 16);
  }

  f32x4 acc[4][2] = {};
  for (int kk = 0; kk < 512; kk += 64) {
    __syncthreads();
#pragma unroll
    for (int c = 0; c < 4; ++c) {
      int u = c * 256 + t, r = u >> 3, s = u & 7;
      *(bf16x8*)((char*)AtS + (size_t)r * 128 + (s ^ (r & 7)) * 16) = areg[c];
    }
#pragma unroll
    for (int c = 0; c < 2; ++c) {
      int u = c * 256 + t, r = u >> 3, s = u & 7;
      *(bf16x8*)((char*)BtS + (size_t)r * 128 + (s ^ (r & 7)) * 16) = breg[c];
    }
    __syncthreads();

    if (kk + 64 < 512) {
      size_t cb = (size_t)(kk + 64) * 2;
#pragma unroll
      for (int c = 0; c < 4; ++c) {
        int u = c * 256 + t, r = u >> 3, s = u & 7;
        areg[c] = *(const bf16x8*)(Ag + (size_t)r * 1024 + cb + s * 16);
      }
#pragma unroll
      for (int c = 0; c < 2; ++c) {
        int u = c * 256 + t, r = u >> 3, s = u & 7;
        breg[c] = *(const bf16x8*)(Bg + (size_t)r * 1024 + cb + s * 16);
      }
    }

#pragma unroll
    for (int kf = 0; kf < 2; ++kf) {
      bf16x8 af[4], bfr[2];
#pragma unroll
      for (int rf = 0; rf < 4; ++rf) {
        int r = wr * 64 + rf * 16 + c16;
        int s = (kf * 4 + g) ^ (r & 7);
        af[rf] = *(const bf16x8*)((const char*)AtS + (size_t)r * 128 + s * 16);
      }
#pragma unroll
      for (int cf = 0; cf < 2; ++cf) {
        int r = wc * 32 + cf * 16 + c16;
        int s = (kf * 4 + g) ^ (r & 7);
        bfr[cf] = *(const bf16x8*)((const char*)BtS + (size_t)r * 128 + s * 16);
      }
      __builtin_amdgcn_s_setprio(1);
#pragma unroll
      for (int rf = 0; rf < 4; ++rf)
#pragma unroll
        for (int cf = 0; cf < 2; ++cf)
          acc[rf][cf] = __builtin_amdgcn_mfma_f32_16x16x32_bf16(af[rf], bfr[cf], acc[rf][cf], 0, 0, 0);
      __builtin_amdgcn_s_setprio(0);
    }
  }

#pragma unroll
  for (int rf = 0; rf < 4; ++rf) {
#pragma unroll
    for (int cf = 0; cf < 2; ++cf) {
      int c = n0 + wc * 32 + cf * 16 + c16;
      int h = c / 192, rem = c % 192;
      float bv = bias[c];
#pragma unroll
      for (int r = 0; r < 4; ++r) {
        int row = m0 + wr * 64 + rf * 16 + g * 4 + r;
        int bidx = row >> 10, ltok = row & 1023;
        int bh = bidx * 8 + h;
        float val = acc[rf][cf][r] + bv;
        if (rem < 64)
          qext[((size_t)bh * 1024 + ltok) * 128 + rem] = f2bf(val * 0.125f);
        else if (rem < 128)
          kext[((size_t)bh * 1024 + ltok) * 128 + (rem - 64)] = f2bf(val);
        else
          vT[((size_t)bh * 64 + (rem - 128)) * 1024 + ltok] = f2bf(val);
      }
    }
  }
}

// ---------------- kernel 4: relative-position features (alpha/beta) ----------------
__global__ void k_relpos(UST* __restrict__ qext, UST* __restrict__ kext) {
  int gid = blockIdx.x * 256 + threadIdx.x;  // 32*1024*32
  int j = gid & 31;
  int l = (gid >> 5) & 1023;
  int bh = gid >> 15;
  // div_term = exp(-2j*ln(10000)/64) = 2^(-2j*log2(10000)/64), fp32 (matches jnp)
  float dd = exp2f((float)(-2 * j) * 0.20762050593046f);
  float ang = (float)l * dd;
  float s = __sinf(ang), c = __cosf(ang);
  UST* qp = qext + ((size_t)bh * 1024 + l) * 128;
  float qs = bf2f(qp[j]), qc = bf2f(qp[32 + j]);   // already scaled by 0.125
  qp[64 + j] = f2bf(qs * s + qc * c);
  qp[96 + j] = f2bf(qc * s - qs * c);
  UST* kp = kext + ((size_t)bh * 1024 + l) * 128;
  kp[64 + j] = f2bf(c);
  kp[96 + j] = f2bf(s);
}

// ---------------- kernel 5: fused flash attention, 32x32x16, in-register P ------
// 4 waves (wq, wk). Swapped QK^T: S^T = mfma(A=K-rows, B=Q-cols) -> each lane
// holds P[q = wq*32+l31][16 keys of its wk half] => scalar row-sum accumulator,
// no cross-lane softmax. P -> PV A-frag via 8 cvt_pk_bf16 + 8 shfl_xor(32)
// (T12): kc0 = lh?[x2,x3,w2,w3]:[w0,w1,x0,x1]; kc1 = lh?[x6,x7,w6,w7]:[w4,w5,x4,x5].
// PV: O[q][d] partial over the wave's 32 keys = mfma(A=P, B=V^T rows). wk acts
// as an extra k-split part (PARTS = 2*SPLITS), merged by k_combine. 2 barriers/iter.
template<int SPLITS>
__global__ __launch_bounds__(256) void k_attn_split(
    const UST* __restrict__ qext, const UST* __restrict__ kext,
    const UST* __restrict__ vT,
    float* __restrict__ Opart, float* __restrict__ ml) {
  int blk = ((blockIdx.x & 7) << 6) | (blockIdx.x >> 3);  // XCD-contiguous bh ranges
  int split = blockIdx.y;
  int qt = blk & 15, bh = blk >> 4;
  int q0 = qt * 64;
  int t = threadIdx.x;
  int lane = t & 63, w = t >> 6;
  int l31 = lane & 31, lh = lane >> 5;
  int wq = w >> 1, wk = w & 1;

  __shared__ UST KtS[64 * 128];    // 16KB; (row, slot s) holds global (row, s^(row&7)) [16B units]
  __shared__ UST VtS[64 * 64];     // 8KB;  [d][k], same swizzle on 128B rows

  // Q (B-operand): lane holds B[kc = c*16 + lh*8 + e][n = q = wq*32 + l31]
  const UST* qbase = qext + ((size_t)bh * 1024 + q0 + wq * 32 + l31) * 128 + lh * 8;
  bf16x8 qf[8];
#pragma unroll
  for (int c = 0; c < 8; ++c) qf[c] = *(const bf16x8*)&qbase[c * 16];

  const char* kgbase = (const char*)(kext + (size_t)bh * 1024 * 128);
  const char* vgbase = (const char*)(vT + (size_t)bh * 64 * 1024);

  f32x16 O[2] = {};
  float l_lane = 0.f;

  int kbeg = split * (LSEQ / SPLITS);
  int kend = kbeg + LSEQ / SPLITS;

  bf16x8 kreg[4], vreg[2];
  {
    const char* kg = kgbase + (size_t)kbeg * 256;
#pragma unroll
    for (int c = 0; c < 4; ++c) {
      int u = c * 256 + t;
      kreg[c] = *(const bf16x8*)(kg + (size_t)(u >> 4) * 256 + (u & 15) * 16);
    }
    const char* vg = vgbase + (size_t)kbeg * 2;
#pragma unroll
    for (int c = 0; c < 2; ++c) {
      int u = c * 256 + t;
      vreg[c] = *(const bf16x8*)(vg + (size_t)(u >> 3) * 2048 + (u & 7) * 16);
    }
  }

  int krow = wk * 32 + l31;   // K-tile row this lane reads (A-operand of QK^T)

  for (int k0 = kbeg; k0 < kend; k0 += 64) {
    __syncthreads();   // B1: previous tile fully consumed
#pragma unroll
    for (int c = 0; c < 4; ++c) {
      int u = c * 256 + t, r = u >> 4, s = u & 15;
      *(bf16x8*)((char*)KtS + (size_t)r * 256 + (s ^ (r & 7)) * 16) = kreg[c];
    }
#pragma unroll
    for (int c = 0; c < 2; ++c) {
      int u = c * 256 + t, r = u >> 3, s = u & 7;
      *(bf16x8*)((char*)VtS + (size_t)r * 128 + (s ^ (r & 7)) * 16) = vreg[c];
    }
    __syncthreads();   // B2: tile visible

    if (k0 + 64 < kend) {   // prefetch next tile; latency hides under compute
      const char* kg = kgbase + (size_t)(k0 + 64) * 256;
#pragma unroll
      for (int c = 0; c < 4; ++c) {
        int u = c * 256 + t;
        kreg[c] = *(const bf16x8*)(kg + (size_t)(u >> 4) * 256 + (u & 15) * 16);
      }
      const char* vg = vgbase + (size_t)(k0 + 64) * 2;
#pragma unroll
      for (int c = 0; c < 2; ++c) {
        int u = c * 256 + t;
        vreg[c] = *(const bf16x8*)(vg + (size_t)(u >> 3) * 2048 + (u & 7) * 16);
      }
    }

    // ---- S^T quadrant = K(32x128) x Q^T (8 x mfma_32x32x16, swapped operands)
    f32x16 sa = {};
#pragma unroll
    for (int kh = 0; kh < 2; ++kh) {
      bf16x8 kfr[4];
#pragma unroll
      for (int kc = 0; kc < 4; ++kc) {
        int slot = ((kh * 4 + kc) * 2 + lh) ^ (krow & 7);
        kfr[kc] = *(const bf16x8*)((const char*)KtS + (size_t)krow * 256 + slot * 16);
      }
      __builtin_amdgcn_s_setprio(1);
#pragma unroll
      for (int kc = 0; kc < 4; ++kc)
        sa = __builtin_amdgcn_mfma_f32_32x32x16_bf16(kfr[kc], qf[kh * 4 + kc], sa, 0, 0, 0);
      __builtin_amdgcn_s_setprio(0);
    }

    // ---- P = exp(S): lane-local row q = wq*32+l31, keys crow(r,lh) of wk half
    float p[16];
#pragma unroll
    for (int i = 0; i < 16; ++i) {
      p[i] = __expf(sa[i]);
      l_lane += p[i];
    }
    // pack pairs and exchange halves with lane^32
    unsigned wv[8], xv[8];
#pragma unroll
    for (int j = 0; j < 8; ++j) wv[j] = cvt_pk_bf16(p[2 * j], p[2 * j + 1]);
#pragma unroll
    for (int j = 0; j < 8; ++j) xv[j] = __shfl_xor((int)wv[j], 32, 64);
    int4 pa0i = lh ? (int4){(int)xv[2], (int)xv[3], (int)wv[2], (int)wv[3]}
                   : (int4){(int)wv[0], (int)wv[1], (int)xv[0], (int)xv[1]};
    int4 pa1i = lh ? (int4){(int)xv[6], (int)xv[7], (int)wv[6], (int)wv[7]}
                   : (int4){(int)wv[4], (int)wv[5], (int)xv[4], (int)xv[5]};
    bf16x8 pa[2] = {*(bf16x8*)&pa0i, *(bf16x8*)&pa1i};

    // ---- O[q][d] += P-frag x V^T rows (2 kc x 2 dn mfma_32x32x16)
#pragma unroll
    for (int dn = 0; dn < 2; ++dn) {
      int d = dn * 32 + l31;
      bf16x8 vf[2];
#pragma unroll
      for (int kc = 0; kc < 2; ++kc) {
        int slot = (wk * 4 + kc * 2 + lh) ^ (d & 7);
        vf[kc] = *(const bf16x8*)((const char*)VtS + (size_t)d * 128 + slot * 16);
      }
      __builtin_amdgcn_s_setprio(1);
#pragma unroll
      for (int kc = 0; kc < 2; ++kc)
        O[dn] = __builtin_amdgcn_mfma_f32_32x32x16_bf16(pa[kc], vf[kc], O[dn], 0, 0, 0);
      __builtin_amdgcn_s_setprio(0);
    }
  }

  // ---- epilogue: part sp = split*2 + wk
  l_lane += __shfl_xor(l_lane, 32, 64);
  int sp = split * 2 + wk;
  if (lh == 0) {
    float* mp = ml + (((size_t)sp * 32 + bh) * 1024 + q0 + wq * 32 + l31) * 2;
    mp[0] = 0.f;
    mp[1] = l_lane;
  }
#pragma unroll
  for (int i = 0; i < 16; ++i) {
    int qrow = q0 + wq * 32 + (i & 3) + 8 * (i >> 2) + 4 * lh;
    float* op = Opart + (((size_t)sp * 32 + bh) * 1024 + qrow) * 64 + l31;
    op[0] = O[0][i];
    op[32] = O[1][i];
  }
}

// ---------------- kernel 6: combine parts ----------------
template<int PARTS>
__global__ void k_combine(const float* __restrict__ Opart, const float* __restrict__ ml,
                          float* __restrict__ out) {
  int gid = blockIdx.x * 256 + threadIdx.x;   // 32*1024*16 threads, 4 floats each
  int dq = (gid & 15) * 4;
  int row = (gid >> 4) & 1023;
  int bh = gid >> 14;
  int b = bh >> 3, h = bh & 7;

  float denom = 0.f;
  float4 acc = {0.f, 0.f, 0.f, 0.f};
#pragma unroll
  for (int s = 0; s < PARTS; ++s) {
    denom += ml[(((size_t)s * 32 + bh) * 1024 + row) * 2 + 1];
    float4 ov = *(const float4*)&Opart[(((size_t)s * 32 + bh) * 1024 + row) * 64 + dq];
    acc.x += ov.x; acc.y += ov.y; acc.z += ov.z; acc.w += ov.w;
  }
  float inv = 1.0f / denom;
  float4 o = {acc.x * inv, acc.y * inv, acc.z * inv, acc.w * inv};
  *(float4*)&out[((size_t)b * 1024 + row) * 512 + h * 64 + dq] = o;
}

extern "C" void kernel_launch(void* const* d_in, const int* in_sizes, int n_in,
                              void* d_out, int out_size, void* d_ws, size_t ws_size,
                              hipStream_t stream) {
  const float* x = (const float*)d_in[0];
  const float* W = (const float*)d_in[1];
  const float* bias = (const float*)d_in[2];
  float* out = (float*)d_out;

  UST* ws = (UST*)d_ws;
  UST* xbf  = ws;                       // 4096*512
  UST* WT   = xbf + 4096 * 512;         // 1536*512
  UST* qext = WT + 1536 * 512;          // 32*1024*128
  UST* kext = qext + 32 * 1024 * 128;   // 32*1024*128
  UST* vT   = kext + 32 * 1024 * 128;   // 32*64*1024
  UST* bf_end = vT + 32 * 64 * 1024;    // 13,369,344 USTs = 26.7 MB

  size_t base_bytes = (size_t)(bf_end - ws) * sizeof(UST);
  size_t per_part = (size_t)32 * 1024 * 66 * sizeof(float);  // O(64) + m,l per row
  int S = 1;   // k-splits; parts = 2*S (wk pair is an implicit extra split)
  if (ws_size >= base_bytes + 4 * per_part) S = 2;

  float* Opart = (float*)bf_end;
  float* ml = Opart + (size_t)(2 * S) * 32 * 1024 * 64;

  k_convert_x<<<dim3(2048), dim3(256), 0, stream>>>(x, xbf);
  k_transpose_W<<<dim3(24, 8), dim3(256), 0, stream>>>(W, WT);
  k_proj<<<dim3(32, 24), dim3(256), 0, stream>>>(xbf, WT, bias, qext, kext, vT);
  k_relpos<<<dim3(4096), dim3(256), 0, stream>>>(qext, kext);

  if (S == 2) {
    k_attn_split<2><<<dim3(512, 2), dim3(256), 0, stream>>>(qext, kext, vT, Opart, ml);
    k_combine<4><<<dim3(2048), dim3(256), 0, stream>>>(Opart, ml, out);
  } else {
    k_attn_split<1><<<dim3(512, 1), dim3(256), 0, stream>>>(qext, kext, vT, Opart, ml);
    k_combine<2><<<dim3(2048), dim3(256), 0, stream>>>(Opart, ml, out);
  }
}

// Round 12
// 59.205 us; speedup vs baseline: 1.1811x; 1.1407x over previous
//
#include <hip/hip_runtime.h>

typedef unsigned short UST;
typedef __attribute__((ext_vector_type(8))) __bf16 bf16x8;
typedef __attribute__((ext_vector_type(4))) float f32x4;
typedef __attribute__((ext_vector_type(16))) float f32x16;

#define NB 4
#define NH 8
#define LSEQ 1024
#define DMODEL 512
#define DH 64

__device__ __forceinline__ UST f2bf(float f) {
  union { float f; unsigned u; } v; v.f = f;
  unsigned u = v.u;
  return (UST)((u + 0x7FFFu + ((u >> 16) & 1u)) >> 16);
}
__device__ __forceinline__ float bf2f(UST h) {
  union { unsigned u; float f; } v; v.u = ((unsigned)h) << 16;
  return v.f;
}
__device__ __forceinline__ unsigned cvt_pk_bf16(float lo, float hi) {
  unsigned r;
  asm volatile("v_cvt_pk_bf16_f32 %0, %1, %2" : "=v"(r) : "v"(lo), "v"(hi));
  return r;
}

// ---------------- kernel 1: x (fp32) -> bf16 ----------------
__global__ void k_convert_x(const float* __restrict__ x, UST* __restrict__ xbf) {
  int i = blockIdx.x * 256 + threadIdx.x;   // 2097152/4 elements
  float4 v = ((const float4*)x)[i];
  ushort4 o;
  o.x = f2bf(v.x); o.y = f2bf(v.y); o.z = f2bf(v.z); o.w = f2bf(v.w);
  ((ushort4*)xbf)[i] = o;
}

// ---------------- kernel 2: W [512][1536] fp32 -> WT [1536][512] bf16 ----------------
__global__ void k_transpose_W(const float* __restrict__ W, UST* __restrict__ WT) {
  __shared__ float tile[64][65];
  int n0 = blockIdx.x * 64;   // over 1536
  int k0 = blockIdx.y * 64;   // over 512
  int tx = threadIdx.x & 63, ty = threadIdx.x >> 6;  // ty 0..3
#pragma unroll
  for (int i = 0; i < 16; ++i) {
    int k = ty + i * 4;
    tile[k][tx] = W[(size_t)(k0 + k) * 1536 + n0 + tx];
  }
  __syncthreads();
#pragma unroll
  for (int i = 0; i < 16; ++i) {
    int n = ty + i * 4;
    WT[(size_t)(n0 + n) * 512 + k0 + tx] = f2bf(tile[tx][n]);
  }
}

// ---------------- kernel 3: projection GEMM + scatter (LDS reg-staged pipeline) ----
// q columns are pre-scaled by 0.125 (=1/sqrt(d_head)); alpha inherits the scale
// linearly in k_relpos, so attention scores come out of MFMA already scaled.
__global__ __launch_bounds__(256) void k_proj(
    const UST* __restrict__ xbf, const UST* __restrict__ WT, const float* __restrict__ bias,
    UST* __restrict__ qext, UST* __restrict__ kext, UST* __restrict__ vT) {
  int m0 = blockIdx.x * 128;  // token tile
  int n0 = blockIdx.y * 64;   // out-col tile
  int t = threadIdx.x;
  int lane = t & 63, w = t >> 6;
  int wr = w >> 1, wc = w & 1;
  int g = lane >> 4, c16 = lane & 15;

  __shared__ UST AtS[128 * 64];  // 16KB; (row, slot s) holds global (row, s^(row&7)) [16B units]
  __shared__ UST BtS[64 * 64];   // 8KB; same swizzle

  const char* Ag = (const char*)(xbf + (size_t)m0 * 512);  // row stride 1024B
  const char* Bg = (const char*)(WT + (size_t)n0 * 512);   // row stride 1024B

  bf16x8 areg[4], breg[2];
#pragma unroll
  for (int c = 0; c < 4; ++c) {
    int u = c * 256 + t, r = u >> 3, s = u & 7;
    areg[c] = *(const bf16x8*)(Ag + (size_t)r * 1024 + s * 16);
  }
#pragma unroll
  for (int c = 0; c < 2; ++c) {
    int u = c * 256 + t, r = u >> 3, s = u & 7;
    breg[c] = *(const bf16x8*)(Bg + (size_t)r * 1024 + s * 16);
  }

  f32x4 acc[4][2] = {};
  for (int kk = 0; kk < 512; kk += 64) {
    __syncthreads();
#pragma unroll
    for (int c = 0; c < 4; ++c) {
      int u = c * 256 + t, r = u >> 3, s = u & 7;
      *(bf16x8*)((char*)AtS + (size_t)r * 128 + (s ^ (r & 7)) * 16) = areg[c];
    }
#pragma unroll
    for (int c = 0; c < 2; ++c) {
      int u = c * 256 + t, r = u >> 3, s = u & 7;
      *(bf16x8*)((char*)BtS + (size_t)r * 128 + (s ^ (r & 7)) * 16) = breg[c];
    }
    __syncthreads();

    if (kk + 64 < 512) {
      size_t cb = (size_t)(kk + 64) * 2;
#pragma unroll
      for (int c = 0; c < 4; ++c) {
        int u = c * 256 + t, r = u >> 3, s = u & 7;
        areg[c] = *(const bf16x8*)(Ag + (size_t)r * 1024 + cb + s * 16);
      }
#pragma unroll
      for (int c = 0; c < 2; ++c) {
        int u = c * 256 + t, r = u >> 3, s = u & 7;
        breg[c] = *(const bf16x8*)(Bg + (size_t)r * 1024 + cb + s * 16);
      }
    }

#pragma unroll
    for (int kf = 0; kf < 2; ++kf) {
      bf16x8 af[4], bfr[2];
#pragma unroll
      for (int rf = 0; rf < 4; ++rf) {
        int r = wr * 64 + rf * 16 + c16;
        int s = (kf * 4 + g) ^ (r & 7);
        af[rf] = *(const bf16x8*)((const char*)AtS + (size_t)r * 128 + s * 16);
      }
#pragma unroll
      for (int cf = 0; cf < 2; ++cf) {
        int r = wc * 32 + cf * 16 + c16;
        int s = (kf * 4 + g) ^ (r & 7);
        bfr[cf] = *(const bf16x8*)((const char*)BtS + (size_t)r * 128 + s * 16);
      }
      __builtin_amdgcn_s_setprio(1);
#pragma unroll
      for (int rf = 0; rf < 4; ++rf)
#pragma unroll
        for (int cf = 0; cf < 2; ++cf)
          acc[rf][cf] = __builtin_amdgcn_mfma_f32_16x16x32_bf16(af[rf], bfr[cf], acc[rf][cf], 0, 0, 0);
      __builtin_amdgcn_s_setprio(0);
    }
  }

#pragma unroll
  for (int rf = 0; rf < 4; ++rf) {
#pragma unroll
    for (int cf = 0; cf < 2; ++cf) {
      int c = n0 + wc * 32 + cf * 16 + c16;
      int h = c / 192, rem = c % 192;
      float bv = bias[c];
#pragma unroll
      for (int r = 0; r < 4; ++r) {
        int row = m0 + wr * 64 + rf * 16 + g * 4 + r;
        int bidx = row >> 10, ltok = row & 1023;
        int bh = bidx * 8 + h;
        float val = acc[rf][cf][r] + bv;
        if (rem < 64)
          qext[((size_t)bh * 1024 + ltok) * 128 + rem] = f2bf(val * 0.125f);
        else if (rem < 128)
          kext[((size_t)bh * 1024 + ltok) * 128 + (rem - 64)] = f2bf(val);
        else
          vT[((size_t)bh * 64 + (rem - 128)) * 1024 + ltok] = f2bf(val);
      }
    }
  }
}

// ---------------- kernel 4: relative-position features (alpha/beta) ----------------
__global__ void k_relpos(UST* __restrict__ qext, UST* __restrict__ kext) {
  int gid = blockIdx.x * 256 + threadIdx.x;  // 32*1024*32
  int j = gid & 31;
  int l = (gid >> 5) & 1023;
  int bh = gid >> 15;
  // div_term = exp(-2j*ln(10000)/64) = 2^(-2j*log2(10000)/64), fp32 (matches jnp)
  float dd = exp2f((float)(-2 * j) * 0.20762050593046f);
  float ang = (float)l * dd;
  float s = __sinf(ang), c = __cosf(ang);
  UST* qp = qext + ((size_t)bh * 1024 + l) * 128;
  float qs = bf2f(qp[j]), qc = bf2f(qp[32 + j]);   // already scaled by 0.125
  qp[64 + j] = f2bf(qs * s + qc * c);
  qp[96 + j] = f2bf(qc * s - qs * c);
  UST* kp = kext + ((size_t)bh * 1024 + l) * 128;
  kp[64 + j] = f2bf(c);
  kp[96 + j] = f2bf(s);
}

// ---------------- kernel 5: fused flash attention, 32x32x16, in-register P ------
// Inner k-loop byte-identical to the R8-verified kernel. Epilogue: in-block
// combine of the wk wave-pair through LDS (KtS reused as 16KB fp32 scratch).
// BUGFIX vs R11: denominators are stored PER ROW in Lsum[wk][wq][32] (written
// lane-indexed where l_lane is valid: q = wq*32+l31) and looked up per OUTPUT
// row crow(i,lh) at write time. R11 wrongly divided row crow by row l31's sum.
__global__ __launch_bounds__(256) void k_attn(
    const UST* __restrict__ qext, const UST* __restrict__ kext,
    const UST* __restrict__ vT, float* __restrict__ out) {
  int blk = ((blockIdx.x & 7) << 6) | (blockIdx.x >> 3);  // XCD-contiguous bh ranges
  int qt = blk & 15, bh = blk >> 4;
  int b = bh >> 3, h = bh & 7;
  int q0 = qt * 64;
  int t = threadIdx.x;
  int lane = t & 63, w = t >> 6;
  int l31 = lane & 31, lh = lane >> 5;
  int wq = w >> 1, wk = w & 1;

  __shared__ UST KtS[64 * 128];    // 16KB; (row, slot s) holds global (row, s^(row&7)) [16B units]
  __shared__ UST VtS[64 * 64];     // 8KB;  [d][k], same swizzle on 128B rows
  __shared__ float Lsum[2][2][32]; // [wk][wq][row within quadrant] half-denominators

  // Q (B-operand): lane holds B[kc = c*16 + lh*8 + e][n = q = wq*32 + l31]
  const UST* qbase = qext + ((size_t)bh * 1024 + q0 + wq * 32 + l31) * 128 + lh * 8;
  bf16x8 qf[8];
#pragma unroll
  for (int c = 0; c < 8; ++c) qf[c] = *(const bf16x8*)&qbase[c * 16];

  const char* kgbase = (const char*)(kext + (size_t)bh * 1024 * 128);
  const char* vgbase = (const char*)(vT + (size_t)bh * 64 * 1024);

  f32x16 O[2] = {};
  float l_lane = 0.f;

  bf16x8 kreg[4], vreg[2];
  {
    const char* kg = kgbase;
#pragma unroll
    for (int c = 0; c < 4; ++c) {
      int u = c * 256 + t;
      kreg[c] = *(const bf16x8*)(kg + (size_t)(u >> 4) * 256 + (u & 15) * 16);
    }
    const char* vg = vgbase;
#pragma unroll
    for (int c = 0; c < 2; ++c) {
      int u = c * 256 + t;
      vreg[c] = *(const bf16x8*)(vg + (size_t)(u >> 3) * 2048 + (u & 7) * 16);
    }
  }

  int krow = wk * 32 + l31;   // K-tile row this lane reads (A-operand of QK^T)

  for (int k0 = 0; k0 < LSEQ; k0 += 64) {
    __syncthreads();   // B1: previous tile fully consumed
#pragma unroll
    for (int c = 0; c < 4; ++c) {
      int u = c * 256 + t, r = u >> 4, s = u & 15;
      *(bf16x8*)((char*)KtS + (size_t)r * 256 + (s ^ (r & 7)) * 16) = kreg[c];
    }
#pragma unroll
    for (int c = 0; c < 2; ++c) {
      int u = c * 256 + t, r = u >> 3, s = u & 7;
      *(bf16x8*)((char*)VtS + (size_t)r * 128 + (s ^ (r & 7)) * 16) = vreg[c];
    }
    __syncthreads();   // B2: tile visible

    if (k0 + 64 < LSEQ) {   // prefetch next tile; latency hides under compute
      const char* kg = kgbase + (size_t)(k0 + 64) * 256;
#pragma unroll
      for (int c = 0; c < 4; ++c) {
        int u = c * 256 + t;
        kreg[c] = *(const bf16x8*)(kg + (size_t)(u >> 4) * 256 + (u & 15) * 16);
      }
      const char* vg = vgbase + (size_t)(k0 + 64) * 2;
#pragma unroll
      for (int c = 0; c < 2; ++c) {
        int u = c * 256 + t;
        vreg[c] = *(const bf16x8*)(vg + (size_t)(u >> 3) * 2048 + (u & 7) * 16);
      }
    }

    // ---- S^T quadrant = K(32x128) x Q^T (8 x mfma_32x32x16, swapped operands)
    f32x16 sa = {};
#pragma unroll
    for (int kh = 0; kh < 2; ++kh) {
      bf16x8 kfr[4];
#pragma unroll
      for (int kc = 0; kc < 4; ++kc) {
        int slot = ((kh * 4 + kc) * 2 + lh) ^ (krow & 7);
        kfr[kc] = *(const bf16x8*)((const char*)KtS + (size_t)krow * 256 + slot * 16);
      }
      __builtin_amdgcn_s_setprio(1);
#pragma unroll
      for (int kc = 0; kc < 4; ++kc)
        sa = __builtin_amdgcn_mfma_f32_32x32x16_bf16(kfr[kc], qf[kh * 4 + kc], sa, 0, 0, 0);
      __builtin_amdgcn_s_setprio(0);
    }

    // ---- P = exp(S): lane-local; pack pairs and exchange halves with lane^32
    float p[16];
#pragma unroll
    for (int i = 0; i < 16; ++i) {
      p[i] = __expf(sa[i]);
      l_lane += p[i];
    }
    unsigned wv[8], xv[8];
#pragma unroll
    for (int j = 0; j < 8; ++j) wv[j] = cvt_pk_bf16(p[2 * j], p[2 * j + 1]);
#pragma unroll
    for (int j = 0; j < 8; ++j) xv[j] = (unsigned)__shfl_xor((int)wv[j], 32, 64);
    int4 pa0i = lh ? (int4){(int)xv[2], (int)xv[3], (int)wv[2], (int)wv[3]}
                   : (int4){(int)wv[0], (int)wv[1], (int)xv[0], (int)xv[1]};
    int4 pa1i = lh ? (int4){(int)xv[6], (int)xv[7], (int)wv[6], (int)wv[7]}
                   : (int4){(int)wv[4], (int)wv[5], (int)xv[4], (int)xv[5]};
    bf16x8 pa[2] = {*(bf16x8*)&pa0i, *(bf16x8*)&pa1i};

    // ---- O[q][d] += P-frag x V^T rows (2 kc x 2 dn mfma_32x32x16)
#pragma unroll
    for (int dn = 0; dn < 2; ++dn) {
      int d = dn * 32 + l31;
      bf16x8 vf[2];
#pragma unroll
      for (int kc = 0; kc < 2; ++kc) {
        int slot = (wk * 4 + kc * 2 + lh) ^ (d & 7);
        vf[kc] = *(const bf16x8*)((const char*)VtS + (size_t)d * 128 + slot * 16);
      }
      __builtin_amdgcn_s_setprio(1);
#pragma unroll
      for (int kc = 0; kc < 2; ++kc)
        O[dn] = __builtin_amdgcn_mfma_f32_32x32x16_bf16(pa[kc], vf[kc], O[dn], 0, 0, 0);
      __builtin_amdgcn_s_setprio(0);
    }
  }

  // ---- epilogue: per-row denominators to LDS, combine wk pair, direct out write
  l_lane += __shfl_xor(l_lane, 32, 64);   // sum over this wave's 32 keys/tile, q = wq*32+l31
  if (lh == 0) Lsum[wk][wq][l31] = l_lane;
  __syncthreads();                        // all tile reads done; Lsum visible
  float* scratch = (float*)KtS;           // 64 q rows x 64 d x f32 = 16KB
  if (wk == 1) {
#pragma unroll
    for (int i = 0; i < 16; ++i) {
      int qr = wq * 32 + ((i & 3) + 8 * (i >> 2) + 4 * lh);
      scratch[qr * 64 + l31] = O[0][i];
      scratch[qr * 64 + 32 + l31] = O[1][i];
    }
  }
  __syncthreads();
  if (wk == 0) {
#pragma unroll
    for (int i = 0; i < 16; ++i) {
      int cr = (i & 3) + 8 * (i >> 2) + 4 * lh;   // row within quadrant (matches O regs)
      int qr = wq * 32 + cr;
      float inv = 1.0f / (Lsum[0][wq][cr] + Lsum[1][wq][cr]);
      float* op = out + ((size_t)b * 1024 + q0 + qr) * 512 + h * 64;
      op[l31] = (O[0][i] + scratch[qr * 64 + l31]) * inv;
      op[32 + l31] = (O[1][i] + scratch[qr * 64 + 32 + l31]) * inv;
    }
  }
}

extern "C" void kernel_launch(void* const* d_in, const int* in_sizes, int n_in,
                              void* d_out, int out_size, void* d_ws, size_t ws_size,
                              hipStream_t stream) {
  const float* x = (const float*)d_in[0];
  const float* W = (const float*)d_in[1];
  const float* bias = (const float*)d_in[2];
  float* out = (float*)d_out;

  UST* ws = (UST*)d_ws;
  UST* xbf  = ws;                       // 4096*512
  UST* WT   = xbf + 4096 * 512;         // 1536*512
  UST* qext = WT + 1536 * 512;          // 32*1024*128
  UST* kext = qext + 32 * 1024 * 128;   // 32*1024*128
  UST* vT   = kext + 32 * 1024 * 128;   // 32*64*1024

  k_convert_x<<<dim3(2048), dim3(256), 0, stream>>>(x, xbf);
  k_transpose_W<<<dim3(24, 8), dim3(256), 0, stream>>>(W, WT);
  k_proj<<<dim3(32, 24), dim3(256), 0, stream>>>(xbf, WT, bias, qext, kext, vT);
  k_relpos<<<dim3(4096), dim3(256), 0, stream>>>(qext, kext);
  k_attn<<<dim3(512), dim3(256), 0, stream>>>(qext, kext, vT, out);
}

// Round 13
// 58.661 us; speedup vs baseline: 1.1920x; 1.0093x over previous
//
#include <hip/hip_runtime.h>

typedef unsigned short UST;
typedef __attribute__((ext_vector_type(8))) __bf16 bf16x8;
typedef __attribute__((ext_vector_type(4))) float f32x4;
typedef __attribute__((ext_vector_type(16))) float f32x16;

#define NB 4
#define NH 8
#define LSEQ 1024
#define DMODEL 512
#define DH 64

__device__ __forceinline__ UST f2bf(float f) {
  union { float f; unsigned u; } v; v.f = f;
  unsigned u = v.u;
  return (UST)((u + 0x7FFFu + ((u >> 16) & 1u)) >> 16);
}
__device__ __forceinline__ float bf2f(UST h) {
  union { unsigned u; float f; } v; v.u = ((unsigned)h) << 16;
  return v.f;
}
__device__ __forceinline__ unsigned cvt_pk_bf16(float lo, float hi) {
  unsigned r;
  asm volatile("v_cvt_pk_bf16_f32 %0, %1, %2" : "=v"(r) : "v"(lo), "v"(hi));
  return r;
}

// ---------------- kernel 1: x (fp32) -> bf16 ----------------
__global__ void k_convert_x(const float* __restrict__ x, UST* __restrict__ xbf) {
  int i = blockIdx.x * 256 + threadIdx.x;   // 2097152/4 elements
  float4 v = ((const float4*)x)[i];
  ushort4 o;
  o.x = f2bf(v.x); o.y = f2bf(v.y); o.z = f2bf(v.z); o.w = f2bf(v.w);
  ((ushort4*)xbf)[i] = o;
}

// ---------------- kernel 2: W [512][1536] fp32 -> WT [1536][512] bf16 ----------------
__global__ void k_transpose_W(const float* __restrict__ W, UST* __restrict__ WT) {
  __shared__ float tile[64][65];
  int n0 = blockIdx.x * 64;   // over 1536
  int k0 = blockIdx.y * 64;   // over 512
  int tx = threadIdx.x & 63, ty = threadIdx.x >> 6;  // ty 0..3
#pragma unroll
  for (int i = 0; i < 16; ++i) {
    int k = ty + i * 4;
    tile[k][tx] = W[(size_t)(k0 + k) * 1536 + n0 + tx];
  }
  __syncthreads();
#pragma unroll
  for (int i = 0; i < 16; ++i) {
    int n = ty + i * 4;
    WT[(size_t)(n0 + n) * 512 + k0 + tx] = f2bf(tile[tx][n]);
  }
}

// ---------------- kernel 3: projection GEMM + scatter (LDS reg-staged pipeline) ----
// q columns are pre-scaled by 0.125 (=1/sqrt(d_head)); alpha inherits the scale
// linearly in k_relpos, so attention scores come out of MFMA already scaled.
// (k_proj's swizzle groups are 2-way only (free per m136) -> left as (r&7).)
__global__ __launch_bounds__(256) void k_proj(
    const UST* __restrict__ xbf, const UST* __restrict__ WT, const float* __restrict__ bias,
    UST* __restrict__ qext, UST* __restrict__ kext, UST* __restrict__ vT) {
  int m0 = blockIdx.x * 128;  // token tile
  int n0 = blockIdx.y * 64;   // out-col tile
  int t = threadIdx.x;
  int lane = t & 63, w = t >> 6;
  int wr = w >> 1, wc = w & 1;
  int g = lane >> 4, c16 = lane & 15;

  __shared__ UST AtS[128 * 64];  // 16KB; (row, slot s) holds global (row, s^(row&7)) [16B units]
  __shared__ UST BtS[64 * 64];   // 8KB; same swizzle

  const char* Ag = (const char*)(xbf + (size_t)m0 * 512);  // row stride 1024B
  const char* Bg = (const char*)(WT + (size_t)n0 * 512);   // row stride 1024B

  bf16x8 areg[4], breg[2];
#pragma unroll
  for (int c = 0; c < 4; ++c) {
    int u = c * 256 + t, r = u >> 3, s = u & 7;
    areg[c] = *(const bf16x8*)(Ag + (size_t)r * 1024 + s * 16);
  }
#pragma unroll
  for (int c = 0; c < 2; ++c) {
    int u = c * 256 + t, r = u >> 3, s = u & 7;
    breg[c] = *(const bf16x8*)(Bg + (size_t)r * 1024 + s * 16);
  }

  f32x4 acc[4][2] = {};
  for (int kk = 0; kk < 512; kk += 64) {
    __syncthreads();
#pragma unroll
    for (int c = 0; c < 4; ++c) {
      int u = c * 256 + t, r = u >> 3, s = u & 7;
      *(bf16x8*)((char*)AtS + (size_t)r * 128 + (s ^ (r & 7)) * 16) = areg[c];
    }
#pragma unroll
    for (int c = 0; c < 2; ++c) {
      int u = c * 256 + t, r = u >> 3, s = u & 7;
      *(bf16x8*)((char*)BtS + (size_t)r * 128 + (s ^ (r & 7)) * 16) = breg[c];
    }
    __syncthreads();

    if (kk + 64 < 512) {
      size_t cb = (size_t)(kk + 64) * 2;
#pragma unroll
      for (int c = 0; c < 4; ++c) {
        int u = c * 256 + t, r = u >> 3, s = u & 7;
        areg[c] = *(const bf16x8*)(Ag + (size_t)r * 1024 + cb + s * 16);
      }
#pragma unroll
      for (int c = 0; c < 2; ++c) {
        int u = c * 256 + t, r = u >> 3, s = u & 7;
        breg[c] = *(const bf16x8*)(Bg + (size_t)r * 1024 + cb + s * 16);
      }
    }

#pragma unroll
    for (int kf = 0; kf < 2; ++kf) {
      bf16x8 af[4], bfr[2];
#pragma unroll
      for (int rf = 0; rf < 4; ++rf) {
        int r = wr * 64 + rf * 16 + c16;
        int s = (kf * 4 + g) ^ (r & 7);
        af[rf] = *(const bf16x8*)((const char*)AtS + (size_t)r * 128 + s * 16);
      }
#pragma unroll
      for (int cf = 0; cf < 2; ++cf) {
        int r = wc * 32 + cf * 16 + c16;
        int s = (kf * 4 + g) ^ (r & 7);
        bfr[cf] = *(const bf16x8*)((const char*)BtS + (size_t)r * 128 + s * 16);
      }
      __builtin_amdgcn_s_setprio(1);
#pragma unroll
      for (int rf = 0; rf < 4; ++rf)
#pragma unroll
        for (int cf = 0; cf < 2; ++cf)
          acc[rf][cf] = __builtin_amdgcn_mfma_f32_16x16x32_bf16(af[rf], bfr[cf], acc[rf][cf], 0, 0, 0);
      __builtin_amdgcn_s_setprio(0);
    }
  }

#pragma unroll
  for (int rf = 0; rf < 4; ++rf) {
#pragma unroll
    for (int cf = 0; cf < 2; ++cf) {
      int c = n0 + wc * 32 + cf * 16 + c16;
      int h = c / 192, rem = c % 192;
      float bv = bias[c];
#pragma unroll
      for (int r = 0; r < 4; ++r) {
        int row = m0 + wr * 64 + rf * 16 + g * 4 + r;
        int bidx = row >> 10, ltok = row & 1023;
        int bh = bidx * 8 + h;
        float val = acc[rf][cf][r] + bv;
        if (rem < 64)
          qext[((size_t)bh * 1024 + ltok) * 128 + rem] = f2bf(val * 0.125f);
        else if (rem < 128)
          kext[((size_t)bh * 1024 + ltok) * 128 + (rem - 64)] = f2bf(val);
        else
          vT[((size_t)bh * 64 + (rem - 128)) * 1024 + ltok] = f2bf(val);
      }
    }
  }
}

// ---------------- kernel 4: relative-position features (alpha/beta) ----------------
__global__ void k_relpos(UST* __restrict__ qext, UST* __restrict__ kext) {
  int gid = blockIdx.x * 256 + threadIdx.x;  // 32*1024*32
  int j = gid & 31;
  int l = (gid >> 5) & 1023;
  int bh = gid >> 15;
  // div_term = exp(-2j*ln(10000)/64) = 2^(-2j*log2(10000)/64), fp32 (matches jnp)
  float dd = exp2f((float)(-2 * j) * 0.20762050593046f);
  float ang = (float)l * dd;
  float s = __sinf(ang), c = __cosf(ang);
  UST* qp = qext + ((size_t)bh * 1024 + l) * 128;
  float qs = bf2f(qp[j]), qc = bf2f(qp[32 + j]);   // already scaled by 0.125
  qp[64 + j] = f2bf(qs * s + qc * c);
  qp[96 + j] = f2bf(qc * s - qs * c);
  UST* kp = kext + ((size_t)bh * 1024 + l) * 128;
  kp[64 + j] = f2bf(c);
  kp[96 + j] = f2bf(s);
}

// ---------------- kernel 5: fused flash attention, 32x32x16, in-register P ------
// Identical to the R12-verified kernel EXCEPT the LDS swizzle salt:
// (r&7) -> ((r ^ (r>>3)) & 7) at all four sites (K/V write + K/V read).
// Rationale: frag reads group 4 lanes whose rows differ by 8; (r&7) is identical
// for rows 8 apart -> same slot -> same bank quad -> 4-way conflict (1.58x,
// m136). The new salt differs for rows 8 apart -> conflict-free. Same salt on
// write and read keeps the mapping an involution (pure layout permutation).
__global__ __launch_bounds__(256) void k_attn(
    const UST* __restrict__ qext, const UST* __restrict__ kext,
    const UST* __restrict__ vT, float* __restrict__ out) {
  int blk = ((blockIdx.x & 7) << 6) | (blockIdx.x >> 3);  // XCD-contiguous bh ranges
  int qt = blk & 15, bh = blk >> 4;
  int b = bh >> 3, h = bh & 7;
  int q0 = qt * 64;
  int t = threadIdx.x;
  int lane = t & 63, w = t >> 6;
  int l31 = lane & 31, lh = lane >> 5;
  int wq = w >> 1, wk = w & 1;

  __shared__ UST KtS[64 * 128];    // 16KB; (row, slot s) holds global (row, s^salt(row)) [16B units]
  __shared__ UST VtS[64 * 64];     // 8KB;  [d][k], same swizzle on 128B rows
  __shared__ float Lsum[2][2][32]; // [wk][wq][row within quadrant] half-denominators

  // Q (B-operand): lane holds B[kc = c*16 + lh*8 + e][n = q = wq*32 + l31]
  const UST* qbase = qext + ((size_t)bh * 1024 + q0 + wq * 32 + l31) * 128 + lh * 8;
  bf16x8 qf[8];
#pragma unroll
  for (int c = 0; c < 8; ++c) qf[c] = *(const bf16x8*)&qbase[c * 16];

  const char* kgbase = (const char*)(kext + (size_t)bh * 1024 * 128);
  const char* vgbase = (const char*)(vT + (size_t)bh * 64 * 1024);

  f32x16 O[2] = {};
  float l_lane = 0.f;

  bf16x8 kreg[4], vreg[2];
  {
    const char* kg = kgbase;
#pragma unroll
    for (int c = 0; c < 4; ++c) {
      int u = c * 256 + t;
      kreg[c] = *(const bf16x8*)(kg + (size_t)(u >> 4) * 256 + (u & 15) * 16);
    }
    const char* vg = vgbase;
#pragma unroll
    for (int c = 0; c < 2; ++c) {
      int u = c * 256 + t;
      vreg[c] = *(const bf16x8*)(vg + (size_t)(u >> 3) * 2048 + (u & 7) * 16);
    }
  }

  int krow = wk * 32 + l31;   // K-tile row this lane reads (A-operand of QK^T)
  int ksalt = (krow ^ (krow >> 3)) & 7;

  for (int k0 = 0; k0 < LSEQ; k0 += 64) {
    __syncthreads();   // B1: previous tile fully consumed
#pragma unroll
    for (int c = 0; c < 4; ++c) {
      int u = c * 256 + t, r = u >> 4, s = u & 15;
      *(bf16x8*)((char*)KtS + (size_t)r * 256 + (s ^ ((r ^ (r >> 3)) & 7)) * 16) = kreg[c];
    }
#pragma unroll
    for (int c = 0; c < 2; ++c) {
      int u = c * 256 + t, r = u >> 3, s = u & 7;
      *(bf16x8*)((char*)VtS + (size_t)r * 128 + (s ^ ((r ^ (r >> 3)) & 7)) * 16) = vreg[c];
    }
    __syncthreads();   // B2: tile visible

    if (k0 + 64 < LSEQ) {   // prefetch next tile; latency hides under compute
      const char* kg = kgbase + (size_t)(k0 + 64) * 256;
#pragma unroll
      for (int c = 0; c < 4; ++c) {
        int u = c * 256 + t;
        kreg[c] = *(const bf16x8*)(kg + (size_t)(u >> 4) * 256 + (u & 15) * 16);
      }
      const char* vg = vgbase + (size_t)(k0 + 64) * 2;
#pragma unroll
      for (int c = 0; c < 2; ++c) {
        int u = c * 256 + t;
        vreg[c] = *(const bf16x8*)(vg + (size_t)(u >> 3) * 2048 + (u & 7) * 16);
      }
    }

    // ---- S^T quadrant = K(32x128) x Q^T (8 x mfma_32x32x16, swapped operands)
    f32x16 sa = {};
#pragma unroll
    for (int kh = 0; kh < 2; ++kh) {
      bf16x8 kfr[4];
#pragma unroll
      for (int kc = 0; kc < 4; ++kc) {
        int slot = ((kh * 4 + kc) * 2 + lh) ^ ksalt;
        kfr[kc] = *(const bf16x8*)((const char*)KtS + (size_t)krow * 256 + slot * 16);
      }
      __builtin_amdgcn_s_setprio(1);
#pragma unroll
      for (int kc = 0; kc < 4; ++kc)
        sa = __builtin_amdgcn_mfma_f32_32x32x16_bf16(kfr[kc], qf[kh * 4 + kc], sa, 0, 0, 0);
      __builtin_amdgcn_s_setprio(0);
    }

    // ---- P = exp(S): lane-local; pack pairs and exchange halves with lane^32
    float p[16];
#pragma unroll
    for (int i = 0; i < 16; ++i) {
      p[i] = __expf(sa[i]);
      l_lane += p[i];
    }
    unsigned wv[8], xv[8];
#pragma unroll
    for (int j = 0; j < 8; ++j) wv[j] = cvt_pk_bf16(p[2 * j], p[2 * j + 1]);
#pragma unroll
    for (int j = 0; j < 8; ++j) xv[j] = (unsigned)__shfl_xor((int)wv[j], 32, 64);
    int4 pa0i = lh ? (int4){(int)xv[2], (int)xv[3], (int)wv[2], (int)wv[3]}
                   : (int4){(int)wv[0], (int)wv[1], (int)xv[0], (int)xv[1]};
    int4 pa1i = lh ? (int4){(int)xv[6], (int)xv[7], (int)wv[6], (int)wv[7]}
                   : (int4){(int)wv[4], (int)wv[5], (int)xv[4], (int)xv[5]};
    bf16x8 pa[2] = {*(bf16x8*)&pa0i, *(bf16x8*)&pa1i};

    // ---- O[q][d] += P-frag x V^T rows (2 kc x 2 dn mfma_32x32x16)
#pragma unroll
    for (int dn = 0; dn < 2; ++dn) {
      int d = dn * 32 + l31;
      int dsalt = (d ^ (d >> 3)) & 7;
      bf16x8 vf[2];
#pragma unroll
      for (int kc = 0; kc < 2; ++kc) {
        int slot = (wk * 4 + kc * 2 + lh) ^ dsalt;
        vf[kc] = *(const bf16x8*)((const char*)VtS + (size_t)d * 128 + slot * 16);
      }
      __builtin_amdgcn_s_setprio(1);
#pragma unroll
      for (int kc = 0; kc < 2; ++kc)
        O[dn] = __builtin_amdgcn_mfma_f32_32x32x16_bf16(pa[kc], vf[kc], O[dn], 0, 0, 0);
      __builtin_amdgcn_s_setprio(0);
    }
  }

  // ---- epilogue: per-row denominators to LDS, combine wk pair, direct out write
  l_lane += __shfl_xor(l_lane, 32, 64);   // sum over this wave's 32 keys/tile, q = wq*32+l31
  if (lh == 0) Lsum[wk][wq][l31] = l_lane;
  __syncthreads();                        // all tile reads done; Lsum visible
  float* scratch = (float*)KtS;           // 64 q rows x 64 d x f32 = 16KB
  if (wk == 1) {
#pragma unroll
    for (int i = 0; i < 16; ++i) {
      int qr = wq * 32 + ((i & 3) + 8 * (i >> 2) + 4 * lh);
      scratch[qr * 64 + l31] = O[0][i];
      scratch[qr * 64 + 32 + l31] = O[1][i];
    }
  }
  __syncthreads();
  if (wk == 0) {
#pragma unroll
    for (int i = 0; i < 16; ++i) {
      int cr = (i & 3) + 8 * (i >> 2) + 4 * lh;   // row within quadrant (matches O regs)
      int qr = wq * 32 + cr;
      float inv = 1.0f / (Lsum[0][wq][cr] + Lsum[1][wq][cr]);
      float* op = out + ((size_t)b * 1024 + q0 + qr) * 512 + h * 64;
      op[l31] = (O[0][i] + scratch[qr * 64 + l31]) * inv;
      op[32 + l31] = (O[1][i] + scratch[qr * 64 + 32 + l31]) * inv;
    }
  }
}

extern "C" void kernel_launch(void* const* d_in, const int* in_sizes, int n_in,
                              void* d_out, int out_size, void* d_ws, size_t ws_size,
                              hipStream_t stream) {
  const float* x = (const float*)d_in[0];
  const float* W = (const float*)d_in[1];
  const float* bias = (const float*)d_in[2];
  float* out = (float*)d_out;

  UST* ws = (UST*)d_ws;
  UST* xbf  = ws;                       // 4096*512
  UST* WT   = xbf + 4096 * 512;         // 1536*512
  UST* qext = WT + 1536 * 512;          // 32*1024*128
  UST* kext = qext + 32 * 1024 * 128;   // 32*1024*128
  UST* vT   = kext + 32 * 1024 * 128;   // 32*64*1024

  k_convert_x<<<dim3(2048), dim3(256), 0, stream>>>(x, xbf);
  k_transpose_W<<<dim3(24, 8), dim3(256), 0, stream>>>(W, WT);
  k_proj<<<dim3(32, 24), dim3(256), 0, stream>>>(xbf, WT, bias, qext, kext, vT);
  k_relpos<<<dim3(4096), dim3(256), 0, stream>>>(qext, kext);
  k_attn<<<dim3(512), dim3(256), 0, stream>>>(qext, kext, vT, out);
}

// Round 15
// 58.047 us; speedup vs baseline: 1.2046x; 1.0106x over previous
//
#include <hip/hip_runtime.h>

typedef unsigned short UST;
typedef __attribute__((ext_vector_type(8))) __bf16 bf16x8;
typedef __attribute__((ext_vector_type(4))) float f32x4;
typedef __attribute__((ext_vector_type(16))) float f32x16;

#define NB 4
#define NH 8
#define LSEQ 1024
#define DMODEL 512
#define DH 64

__device__ __forceinline__ UST f2bf(float f) {
  union { float f; unsigned u; } v; v.f = f;
  unsigned u = v.u;
  return (UST)((u + 0x7FFFu + ((u >> 16) & 1u)) >> 16);
}
__device__ __forceinline__ float bf2f(UST h) {
  union { unsigned u; float f; } v; v.u = ((unsigned)h) << 16;
  return v.f;
}
__device__ __forceinline__ unsigned cvt_pk_bf16(float lo, float hi) {
  unsigned r;
  asm volatile("v_cvt_pk_bf16_f32 %0, %1, %2" : "=v"(r) : "v"(lo), "v"(hi));
  return r;
}

// ---------------- kernel 1: x (fp32) -> bf16 ----------------
__global__ void k_convert_x(const float* __restrict__ x, UST* __restrict__ xbf) {
  int i = blockIdx.x * 256 + threadIdx.x;   // 2097152/4 elements
  float4 v = ((const float4*)x)[i];
  ushort4 o;
  o.x = f2bf(v.x); o.y = f2bf(v.y); o.z = f2bf(v.z); o.w = f2bf(v.w);
  ((ushort4*)xbf)[i] = o;
}

// ---------------- kernel 2: W [512][1536] fp32 -> WT [1536][512] bf16 ----------------
__global__ void k_transpose_W(const float* __restrict__ W, UST* __restrict__ WT) {
  __shared__ float tile[64][65];
  int n0 = blockIdx.x * 64;   // over 1536
  int k0 = blockIdx.y * 64;   // over 512
  int tx = threadIdx.x & 63, ty = threadIdx.x >> 6;  // ty 0..3
#pragma unroll
  for (int i = 0; i < 16; ++i) {
    int k = ty + i * 4;
    tile[k][tx] = W[(size_t)(k0 + k) * 1536 + n0 + tx];
  }
  __syncthreads();
#pragma unroll
  for (int i = 0; i < 16; ++i) {
    int n = ty + i * 4;
    WT[(size_t)(n0 + n) * 512 + k0 + tx] = f2bf(tile[tx][n]);
  }
}

// ---------------- kernel 3: projection GEMM + scatter (LDS reg-staged pipeline) ----
// q columns are pre-scaled by 0.125 (=1/sqrt(d_head)); alpha inherits the scale
// linearly in k_relpos, so attention scores come out of MFMA already scaled.
__global__ __launch_bounds__(256) void k_proj(
    const UST* __restrict__ xbf, const UST* __restrict__ WT, const float* __restrict__ bias,
    UST* __restrict__ qext, UST* __restrict__ kext, UST* __restrict__ vT) {
  int m0 = blockIdx.x * 128;  // token tile
  int n0 = blockIdx.y * 64;   // out-col tile
  int t = threadIdx.x;
  int lane = t & 63, w = t >> 6;
  int wr = w >> 1, wc = w & 1;
  int g = lane >> 4, c16 = lane & 15;

  __shared__ UST AtS[128 * 64];  // 16KB; (row, slot s) holds global (row, s^(row&7)) [16B units]
  __shared__ UST BtS[64 * 64];   // 8KB; same swizzle

  const char* Ag = (const char*)(xbf + (size_t)m0 * 512);  // row stride 1024B
  const char* Bg = (const char*)(WT + (size_t)n0 * 512);   // row stride 1024B

  bf16x8 areg[4], breg[2];
#pragma unroll
  for (int c = 0; c < 4; ++c) {
    int u = c * 256 + t, r = u >> 3, s = u & 7;
    areg[c] = *(const bf16x8*)(Ag + (size_t)r * 1024 + s * 16);
  }
#pragma unroll
  for (int c = 0; c < 2; ++c) {
    int u = c * 256 + t, r = u >> 3, s = u & 7;
    breg[c] = *(const bf16x8*)(Bg + (size_t)r * 1024 + s * 16);
  }

  f32x4 acc[4][2] = {};
  for (int kk = 0; kk < 512; kk += 64) {
    __syncthreads();
#pragma unroll
    for (int c = 0; c < 4; ++c) {
      int u = c * 256 + t, r = u >> 3, s = u & 7;
      *(bf16x8*)((char*)AtS + (size_t)r * 128 + (s ^ (r & 7)) * 16) = areg[c];
    }
#pragma unroll
    for (int c = 0; c < 2; ++c) {
      int u = c * 256 + t, r = u >> 3, s = u & 7;
      *(bf16x8*)((char*)BtS + (size_t)r * 128 + (s ^ (r & 7)) * 16) = breg[c];
    }
    __syncthreads();

    if (kk + 64 < 512) {
      size_t cb = (size_t)(kk + 64) * 2;
#pragma unroll
      for (int c = 0; c < 4; ++c) {
        int u = c * 256 + t, r = u >> 3, s = u & 7;
        areg[c] = *(const bf16x8*)(Ag + (size_t)r * 1024 + cb + s * 16);
      }
#pragma unroll
      for (int c = 0; c < 2; ++c) {
        int u = c * 256 + t, r = u >> 3, s = u & 7;
        breg[c] = *(const bf16x8*)(Bg + (size_t)r * 1024 + cb + s * 16);
      }
    }

#pragma unroll
    for (int kf = 0; kf < 2; ++kf) {
      bf16x8 af[4], bfr[2];
#pragma unroll
      for (int rf = 0; rf < 4; ++rf) {
        int r = wr * 64 + rf * 16 + c16;
        int s = (kf * 4 + g) ^ (r & 7);
        af[rf] = *(const bf16x8*)((const char*)AtS + (size_t)r * 128 + s * 16);
      }
#pragma unroll
      for (int cf = 0; cf < 2; ++cf) {
        int r = wc * 32 + cf * 16 + c16;
        int s = (kf * 4 + g) ^ (r & 7);
        bfr[cf] = *(const bf16x8*)((const char*)BtS + (size_t)r * 128 + s * 16);
      }
      __builtin_amdgcn_s_setprio(1);
#pragma unroll
      for (int rf = 0; rf < 4; ++rf)
#pragma unroll
        for (int cf = 0; cf < 2; ++cf)
          acc[rf][cf] = __builtin_amdgcn_mfma_f32_16x16x32_bf16(af[rf], bfr[cf], acc[rf][cf], 0, 0, 0);
      __builtin_amdgcn_s_setprio(0);
    }
  }

#pragma unroll
  for (int rf = 0; rf < 4; ++rf) {
#pragma unroll
    for (int cf = 0; cf < 2; ++cf) {
      int c = n0 + wc * 32 + cf * 16 + c16;
      int h = c / 192, rem = c % 192;
      float bv = bias[c];
#pragma unroll
      for (int r = 0; r < 4; ++r) {
        int row = m0 + wr * 64 + rf * 16 + g * 4 + r;
        int bidx = row >> 10, ltok = row & 1023;
        int bh = bidx * 8 + h;
        float val = acc[rf][cf][r] + bv;
        if (rem < 64)
          qext[((size_t)bh * 1024 + ltok) * 128 + rem] = f2bf(val * 0.125f);
        else if (rem < 128)
          kext[((size_t)bh * 1024 + ltok) * 128 + (rem - 64)] = f2bf(val);
        else
          vT[((size_t)bh * 64 + (rem - 128)) * 1024 + ltok] = f2bf(val);
      }
    }
  }
}

// ---------------- kernel 4: relative-position features (alpha/beta) ----------------
__global__ void k_relpos(UST* __restrict__ qext, UST* __restrict__ kext) {
  int gid = blockIdx.x * 256 + threadIdx.x;  // 32*1024*32
  int j = gid & 31;
  int l = (gid >> 5) & 1023;
  int bh = gid >> 15;
  // div_term = exp(-2j*ln(10000)/64) = 2^(-2j*log2(10000)/64), fp32 (matches jnp)
  float dd = exp2f((float)(-2 * j) * 0.20762050593046f);
  float ang = (float)l * dd;
  float s = __sinf(ang), c = __cosf(ang);
  UST* qp = qext + ((size_t)bh * 1024 + l) * 128;
  float qs = bf2f(qp[j]), qc = bf2f(qp[32 + j]);   // already scaled by 0.125
  qp[64 + j] = f2bf(qs * s + qc * c);
  qp[96 + j] = f2bf(qc * s - qs * c);
  UST* kp = kext + ((size_t)bh * 1024 + l) * 128;
  kp[64 + j] = f2bf(c);
  kp[96 + j] = f2bf(s);
}

// ---------------- kernel 5: fused flash attention, 32x32x16, in-register P ------
// R13-verified per-wave math and 256-thread/4-wave layout, with ONE skeleton
// change: double-buffered KtS/VtS (49KB) -> 1 barrier per 64-key iteration.
// Iter n: {compute buf[n&1]; ds_write tile n+1 -> buf[(n+1)&1]; issue loads n+2;
// barrier}. Dbuf invariant: barrier(n) separates compute(n)'s reads of buf[n&1]
// from write(n+2)'s overwrite. Register profile identical to R13 (kreg[4],
// vreg[2]) -- no allocation-pressure delta vs the verified binary.
__global__ __launch_bounds__(256) void k_attn(
    const UST* __restrict__ qext, const UST* __restrict__ kext,
    const UST* __restrict__ vT, float* __restrict__ out) {
  int blk = ((blockIdx.x & 7) << 6) | (blockIdx.x >> 3);  // XCD-contiguous bh ranges
  int qt = blk & 15, bh = blk >> 4;
  int b = bh >> 3, h = bh & 7;
  int q0 = qt * 64;
  int t = threadIdx.x;
  int lane = t & 63, w = t >> 6;
  int l31 = lane & 31, lh = lane >> 5;
  int wq = w >> 1, wk = w & 1;

  __shared__ UST KtS[2][64 * 128];   // 2 x 16KB; (row, slot s) holds (row, s^salt(row)) [16B units]
  __shared__ UST VtS[2][64 * 64];    // 2 x 8KB;  [d][k], same swizzle on 128B rows
  __shared__ float Lsum[2][2][32];   // [wk][wq][row within quadrant] half-denominators

  // Q (B-operand): lane holds B[kc = c*16 + lh*8 + e][n = q = q0 + wq*32 + l31]
  const UST* qbase = qext + ((size_t)bh * 1024 + q0 + wq * 32 + l31) * 128 + lh * 8;
  bf16x8 qf[8];
#pragma unroll
  for (int c = 0; c < 8; ++c) qf[c] = *(const bf16x8*)&qbase[c * 16];

  const char* kgbase = (const char*)(kext + (size_t)bh * 1024 * 128);
  const char* vgbase = (const char*)(vT + (size_t)bh * 64 * 1024);

  f32x16 O[2] = {};
  float l_lane = 0.f;

  bf16x8 kreg[4], vreg[2];
  // ---- prologue: tile 0 -> regs -> buf0; issue tile 1 loads; barrier
#pragma unroll
  for (int c = 0; c < 4; ++c) {
    int u = c * 256 + t;
    kreg[c] = *(const bf16x8*)(kgbase + (size_t)(u >> 4) * 256 + (u & 15) * 16);
  }
#pragma unroll
  for (int c = 0; c < 2; ++c) {
    int u = c * 256 + t;
    vreg[c] = *(const bf16x8*)(vgbase + (size_t)(u >> 3) * 2048 + (u & 7) * 16);
  }
#pragma unroll
  for (int c = 0; c < 4; ++c) {
    int u = c * 256 + t, r = u >> 4, s = u & 15;
    *(bf16x8*)((char*)KtS[0] + (size_t)r * 256 + (s ^ ((r ^ (r >> 3)) & 7)) * 16) = kreg[c];
  }
#pragma unroll
  for (int c = 0; c < 2; ++c) {
    int u = c * 256 + t, r = u >> 3, s = u & 7;
    *(bf16x8*)((char*)VtS[0] + (size_t)r * 128 + (s ^ ((r ^ (r >> 3)) & 7)) * 16) = vreg[c];
  }
#pragma unroll
  for (int c = 0; c < 4; ++c) {
    int u = c * 256 + t;
    kreg[c] = *(const bf16x8*)(kgbase + 64 * 256 + (size_t)(u >> 4) * 256 + (u & 15) * 16);
  }
#pragma unroll
  for (int c = 0; c < 2; ++c) {
    int u = c * 256 + t;
    vreg[c] = *(const bf16x8*)(vgbase + 64 * 2 + (size_t)(u >> 3) * 2048 + (u & 7) * 16);
  }
  __syncthreads();

  int krow = wk * 32 + l31;   // K-tile row this lane reads (A-operand of QK^T)
  int ksalt = (krow ^ (krow >> 3)) & 7;

  for (int it = 0; it < 16; ++it) {
    int cur = it & 1;
    const char* Kb = (const char*)(KtS[cur]);
    const char* Vb = (const char*)(VtS[cur]);

    // ---- S^T quadrant = K(32x128) x Q^T (8 x mfma_32x32x16, swapped operands)
    f32x16 sa = {};
#pragma unroll
    for (int kh = 0; kh < 2; ++kh) {
      bf16x8 kfr[4];
#pragma unroll
      for (int kc = 0; kc < 4; ++kc) {
        int slot = ((kh * 4 + kc) * 2 + lh) ^ ksalt;
        kfr[kc] = *(const bf16x8*)(Kb + (size_t)krow * 256 + slot * 16);
      }
      __builtin_amdgcn_s_setprio(1);
#pragma unroll
      for (int kc = 0; kc < 4; ++kc)
        sa = __builtin_amdgcn_mfma_f32_32x32x16_bf16(kfr[kc], qf[kh * 4 + kc], sa, 0, 0, 0);
      __builtin_amdgcn_s_setprio(0);
    }

    // ---- P = exp(S): lane-local; pack pairs and exchange halves with lane^32
    float p[16];
#pragma unroll
    for (int i = 0; i < 16; ++i) {
      p[i] = __expf(sa[i]);
      l_lane += p[i];
    }
    unsigned wv[8], xv[8];
#pragma unroll
    for (int j = 0; j < 8; ++j) wv[j] = cvt_pk_bf16(p[2 * j], p[2 * j + 1]);
#pragma unroll
    for (int j = 0; j < 8; ++j) xv[j] = (unsigned)__shfl_xor((int)wv[j], 32, 64);
    int4 pa0i = lh ? (int4){(int)xv[2], (int)xv[3], (int)wv[2], (int)wv[3]}
                   : (int4){(int)wv[0], (int)wv[1], (int)xv[0], (int)xv[1]};
    int4 pa1i = lh ? (int4){(int)xv[6], (int)xv[7], (int)wv[6], (int)wv[7]}
                   : (int4){(int)wv[4], (int)wv[5], (int)xv[4], (int)xv[5]};
    bf16x8 pa[2] = {*(bf16x8*)&pa0i, *(bf16x8*)&pa1i};

    // ---- O[q][d] += P-frag x V^T rows (2 kc x 2 dn mfma_32x32x16)
#pragma unroll
    for (int dn = 0; dn < 2; ++dn) {
      int d = dn * 32 + l31;
      int dsalt = (d ^ (d >> 3)) & 7;
      bf16x8 vf[2];
#pragma unroll
      for (int kc = 0; kc < 2; ++kc) {
        int slot = (wk * 4 + kc * 2 + lh) ^ dsalt;
        vf[kc] = *(const bf16x8*)(Vb + (size_t)d * 128 + slot * 16);
      }
      __builtin_amdgcn_s_setprio(1);
#pragma unroll
      for (int kc = 0; kc < 2; ++kc)
        O[dn] = __builtin_amdgcn_mfma_f32_32x32x16_bf16(pa[kc], vf[kc], O[dn], 0, 0, 0);
      __builtin_amdgcn_s_setprio(0);
    }

    // ---- stage tile it+1 into buf[cur^1]; issue loads for tile it+2
    if (it < 15) {
      char* Kw = (char*)(KtS[cur ^ 1]);
      char* Vw = (char*)(VtS[cur ^ 1]);
#pragma unroll
      for (int c = 0; c < 4; ++c) {
        int u = c * 256 + t, r = u >> 4, s = u & 15;
        *(bf16x8*)(Kw + (size_t)r * 256 + (s ^ ((r ^ (r >> 3)) & 7)) * 16) = kreg[c];
      }
#pragma unroll
      for (int c = 0; c < 2; ++c) {
        int u = c * 256 + t, r = u >> 3, s = u & 7;
        *(bf16x8*)(Vw + (size_t)r * 128 + (s ^ ((r ^ (r >> 3)) & 7)) * 16) = vreg[c];
      }
      if (it < 14) {
        const char* kg = kgbase + (size_t)(it + 2) * 64 * 256;
#pragma unroll
        for (int c = 0; c < 4; ++c) {
          int u = c * 256 + t;
          kreg[c] = *(const bf16x8*)(kg + (size_t)(u >> 4) * 256 + (u & 15) * 16);
        }
        const char* vg = vgbase + (size_t)(it + 2) * 64 * 2;
#pragma unroll
        for (int c = 0; c < 2; ++c) {
          int u = c * 256 + t;
          vreg[c] = *(const bf16x8*)(vg + (size_t)(u >> 3) * 2048 + (u & 7) * 16);
        }
      }
    }
    __syncthreads();
  }

  // ---- epilogue: per-row denominators to LDS, combine wk pair, direct out write
  l_lane += __shfl_xor(l_lane, 32, 64);   // sum over this wave's 32 keys/tile, q = q0+wq*32+l31
  if (lh == 0) Lsum[wk][wq][l31] = l_lane;
  float* scratch = (float*)KtS[0];        // 64 q rows x 64 d x f32 = 16KB (last reads hit buf1)
  if (wk == 1) {
#pragma unroll
    for (int i = 0; i < 16; ++i) {
      int qr = wq * 32 + ((i & 3) + 8 * (i >> 2) + 4 * lh);
      scratch[qr * 64 + l31] = O[0][i];
      scratch[qr * 64 + 32 + l31] = O[1][i];
    }
  }
  __syncthreads();
  if (wk == 0) {
#pragma unroll
    for (int i = 0; i < 16; ++i) {
      int cr = (i & 3) + 8 * (i >> 2) + 4 * lh;   // row within quadrant (matches O regs)
      int qr = wq * 32 + cr;
      float inv = 1.0f / (Lsum[0][wq][cr] + Lsum[1][wq][cr]);
      float* op = out + ((size_t)b * 1024 + q0 + qr) * 512 + h * 64;
      op[l31] = (O[0][i] + scratch[qr * 64 + l31]) * inv;
      op[32 + l31] = (O[1][i] + scratch[qr * 64 + 32 + l31]) * inv;
    }
  }
}

extern "C" void kernel_launch(void* const* d_in, const int* in_sizes, int n_in,
                              void* d_out, int out_size, void* d_ws, size_t ws_size,
                              hipStream_t stream) {
  const float* x = (const float*)d_in[0];
  const float* W = (const float*)d_in[1];
  const float* bias = (const float*)d_in[2];
  float* out = (float*)d_out;

  UST* ws = (UST*)d_ws;
  UST* xbf  = ws;                       // 4096*512
  UST* WT   = xbf + 4096 * 512;         // 1536*512
  UST* qext = WT + 1536 * 512;          // 32*1024*128
  UST* kext = qext + 32 * 1024 * 128;   // 32*1024*128
  UST* vT   = kext + 32 * 1024 * 128;   // 32*64*1024

  k_convert_x<<<dim3(2048), dim3(256), 0, stream>>>(x, xbf);
  k_transpose_W<<<dim3(24, 8), dim3(256), 0, stream>>>(W, WT);
  k_proj<<<dim3(32, 24), dim3(256), 0, stream>>>(xbf, WT, bias, qext, kext, vT);
  k_relpos<<<dim3(4096), dim3(256), 0, stream>>>(qext, kext);
  k_attn<<<dim3(512), dim3(256), 0, stream>>>(qext, kext, vT, out);
}

// Round 16
// 56.605 us; speedup vs baseline: 1.2353x; 1.0255x over previous
//
#include <hip/hip_runtime.h>

typedef unsigned short UST;
typedef __attribute__((ext_vector_type(8))) __bf16 bf16x8;
typedef __attribute__((ext_vector_type(4))) float f32x4;
typedef __attribute__((ext_vector_type(16))) float f32x16;

#define NB 4
#define NH 8
#define LSEQ 1024
#define DMODEL 512
#define DH 64

__device__ __forceinline__ UST f2bf(float f) {
  union { float f; unsigned u; } v; v.f = f;
  unsigned u = v.u;
  return (UST)((u + 0x7FFFu + ((u >> 16) & 1u)) >> 16);
}
__device__ __forceinline__ float bf2f(UST h) {
  union { unsigned u; float f; } v; v.u = ((unsigned)h) << 16;
  return v.f;
}
__device__ __forceinline__ unsigned cvt_pk_bf16(float lo, float hi) {
  unsigned r;
  asm volatile("v_cvt_pk_bf16_f32 %0, %1, %2" : "=v"(r) : "v"(lo), "v"(hi));
  return r;
}

// ---------------- kernel 1: x (fp32) -> bf16, plus beta fill of kext ----------------
// blocks 0..2047: convert x. blocks 2048..6143: kext[bh][l][64+j]=cos(l*dd_j),
// [96+j]=sin(l*dd_j) (q-independent relative-position features; expressions
// identical to the old k_relpos).
__global__ void k_convert_x(const float* __restrict__ x, UST* __restrict__ xbf,
                            UST* __restrict__ kext) {
  int bid = blockIdx.x;
  if (bid < 2048) {
    int i = bid * 256 + threadIdx.x;   // 2097152/4 elements
    float4 v = ((const float4*)x)[i];
    ushort4 o;
    o.x = f2bf(v.x); o.y = f2bf(v.y); o.z = f2bf(v.z); o.w = f2bf(v.w);
    ((ushort4*)xbf)[i] = o;
  } else {
    int gid = (bid - 2048) * 256 + threadIdx.x;  // 32*1024*32
    int j = gid & 31;
    int l = (gid >> 5) & 1023;
    int bh = gid >> 15;
    float dd = exp2f((float)(-2 * j) * 0.20762050593046f);
    float ang = (float)l * dd;
    float s = __sinf(ang), c = __cosf(ang);
    UST* kp = kext + ((size_t)bh * 1024 + l) * 128;
    kp[64 + j] = f2bf(c);
    kp[96 + j] = f2bf(s);
  }
}

// ---------------- kernel 2: W [512][1536] fp32 -> WT [1536][512] bf16 ----------------
__global__ void k_transpose_W(const float* __restrict__ W, UST* __restrict__ WT) {
  __shared__ float tile[64][65];
  int n0 = blockIdx.x * 64;   // over 1536
  int k0 = blockIdx.y * 64;   // over 512
  int tx = threadIdx.x & 63, ty = threadIdx.x >> 6;  // ty 0..3
#pragma unroll
  for (int i = 0; i < 16; ++i) {
    int k = ty + i * 4;
    tile[k][tx] = W[(size_t)(k0 + k) * 1536 + n0 + tx];
  }
  __syncthreads();
#pragma unroll
  for (int i = 0; i < 16; ++i) {
    int n = ty + i * 4;
    WT[(size_t)(n0 + n) * 512 + k0 + tx] = f2bf(tile[tx][n]);
  }
}

// ---------------- kernel 3: projection GEMM + scatter + fused alpha ----------------
// q columns pre-scaled by 0.125. NEW: blocks with blockIdx.y%3==0 hold exactly
// the 64 q-columns of head y/3 (192=3*64); after the main loop they stash the
// scaled bf16 q tile into AtS (dead, barrier-protected) and compute qext cols
// 64..127 (alpha) with the exact k_relpos expressions -> k_relpos deleted.
__global__ __launch_bounds__(256) void k_proj(
    const UST* __restrict__ xbf, const UST* __restrict__ WT, const float* __restrict__ bias,
    UST* __restrict__ qext, UST* __restrict__ kext, UST* __restrict__ vT) {
  int m0 = blockIdx.x * 128;  // token tile
  int n0 = blockIdx.y * 64;   // out-col tile
  int t = threadIdx.x;
  int lane = t & 63, w = t >> 6;
  int wr = w >> 1, wc = w & 1;
  int g = lane >> 4, c16 = lane & 15;

  __shared__ UST AtS[128 * 64];  // 16KB; (row, slot s) holds global (row, s^(row&7)) [16B units]
  __shared__ UST BtS[64 * 64];   // 8KB; same swizzle

  const char* Ag = (const char*)(xbf + (size_t)m0 * 512);  // row stride 1024B
  const char* Bg = (const char*)(WT + (size_t)n0 * 512);   // row stride 1024B

  bf16x8 areg[4], breg[2];
#pragma unroll
  for (int c = 0; c < 4; ++c) {
    int u = c * 256 + t, r = u >> 3, s = u & 7;
    areg[c] = *(const bf16x8*)(Ag + (size_t)r * 1024 + s * 16);
  }
#pragma unroll
  for (int c = 0; c < 2; ++c) {
    int u = c * 256 + t, r = u >> 3, s = u & 7;
    breg[c] = *(const bf16x8*)(Bg + (size_t)r * 1024 + s * 16);
  }

  f32x4 acc[4][2] = {};
  for (int kk = 0; kk < 512; kk += 64) {
    __syncthreads();
#pragma unroll
    for (int c = 0; c < 4; ++c) {
      int u = c * 256 + t, r = u >> 3, s = u & 7;
      *(bf16x8*)((char*)AtS + (size_t)r * 128 + (s ^ (r & 7)) * 16) = areg[c];
    }
#pragma unroll
    for (int c = 0; c < 2; ++c) {
      int u = c * 256 + t, r = u >> 3, s = u & 7;
      *(bf16x8*)((char*)BtS + (size_t)r * 128 + (s ^ (r & 7)) * 16) = breg[c];
    }
    __syncthreads();

    if (kk + 64 < 512) {
      size_t cb = (size_t)(kk + 64) * 2;
#pragma unroll
      for (int c = 0; c < 4; ++c) {
        int u = c * 256 + t, r = u >> 3, s = u & 7;
        areg[c] = *(const bf16x8*)(Ag + (size_t)r * 1024 + cb + s * 16);
      }
#pragma unroll
      for (int c = 0; c < 2; ++c) {
        int u = c * 256 + t, r = u >> 3, s = u & 7;
        breg[c] = *(const bf16x8*)(Bg + (size_t)r * 1024 + cb + s * 16);
      }
    }

#pragma unroll
    for (int kf = 0; kf < 2; ++kf) {
      bf16x8 af[4], bfr[2];
#pragma unroll
      for (int rf = 0; rf < 4; ++rf) {
        int r = wr * 64 + rf * 16 + c16;
        int s = (kf * 4 + g) ^ (r & 7);
        af[rf] = *(const bf16x8*)((const char*)AtS + (size_t)r * 128 + s * 16);
      }
#pragma unroll
      for (int cf = 0; cf < 2; ++cf) {
        int r = wc * 32 + cf * 16 + c16;
        int s = (kf * 4 + g) ^ (r & 7);
        bfr[cf] = *(const bf16x8*)((const char*)BtS + (size_t)r * 128 + s * 16);
      }
      __builtin_amdgcn_s_setprio(1);
#pragma unroll
      for (int rf = 0; rf < 4; ++rf)
#pragma unroll
        for (int cf = 0; cf < 2; ++cf)
          acc[rf][cf] = __builtin_amdgcn_mfma_f32_16x16x32_bf16(af[rf], bfr[cf], acc[rf][cf], 0, 0, 0);
      __builtin_amdgcn_s_setprio(0);
    }
  }

  bool doalpha = (blockIdx.y % 3 == 0);   // block-uniform
  if (doalpha) __syncthreads();           // last MFMA reads of AtS done before stash

#pragma unroll
  for (int rf = 0; rf < 4; ++rf) {
#pragma unroll
    for (int cf = 0; cf < 2; ++cf) {
      int c = n0 + wc * 32 + cf * 16 + c16;
      int h = c / 192, rem = c % 192;
      float bv = bias[c];
#pragma unroll
      for (int r = 0; r < 4; ++r) {
        int row = m0 + wr * 64 + rf * 16 + g * 4 + r;
        int bidx = row >> 10, ltok = row & 1023;
        int bh = bidx * 8 + h;
        float val = acc[rf][cf][r] + bv;
        if (rem < 64) {
          UST qv = f2bf(val * 0.125f);
          qext[((size_t)bh * 1024 + ltok) * 128 + rem] = qv;
          if (doalpha)  // stash scaled q for alpha (rem==local col for y%3==0)
            AtS[(size_t)(row - m0) * 64 + rem] = qv;
        } else if (rem < 128)
          kext[((size_t)bh * 1024 + ltok) * 128 + (rem - 64)] = f2bf(val);
        else
          vT[((size_t)bh * 64 + (rem - 128)) * 1024 + ltok] = f2bf(val);
      }
    }
  }

  if (doalpha) {
    __syncthreads();                      // stash complete
    int hh = blockIdx.y / 3;              // head
    int rr = t >> 1;                      // local row 0..127
    int row = m0 + rr;
    int bidx = row >> 10, ltok = row & 1023;
    int bh = bidx * 8 + hh;
    UST* qp = qext + ((size_t)bh * 1024 + ltok) * 128;
#pragma unroll
    for (int i = 0; i < 16; ++i) {
      int j = (t & 1) * 16 + i;
      float dd = exp2f((float)(-2 * j) * 0.20762050593046f);
      float ang = (float)ltok * dd;
      float s = __sinf(ang), c = __cosf(ang);
      float qs = bf2f(AtS[(size_t)rr * 64 + j]);
      float qc = bf2f(AtS[(size_t)rr * 64 + 32 + j]);
      qp[64 + j] = f2bf(qs * s + qc * c);
      qp[96 + j] = f2bf(qc * s - qs * c);
    }
  }
}

// ---------------- kernel 5: fused flash attention (R15-verified, unchanged) ------
__global__ __launch_bounds__(256) void k_attn(
    const UST* __restrict__ qext, const UST* __restrict__ kext,
    const UST* __restrict__ vT, float* __restrict__ out) {
  int blk = ((blockIdx.x & 7) << 6) | (blockIdx.x >> 3);  // XCD-contiguous bh ranges
  int qt = blk & 15, bh = blk >> 4;
  int b = bh >> 3, h = bh & 7;
  int q0 = qt * 64;
  int t = threadIdx.x;
  int lane = t & 63, w = t >> 6;
  int l31 = lane & 31, lh = lane >> 5;
  int wq = w >> 1, wk = w & 1;

  __shared__ UST KtS[2][64 * 128];   // 2 x 16KB
  __shared__ UST VtS[2][64 * 64];    // 2 x 8KB
  __shared__ float Lsum[2][2][32];   // [wk][wq][row]

  const UST* qbase = qext + ((size_t)bh * 1024 + q0 + wq * 32 + l31) * 128 + lh * 8;
  bf16x8 qf[8];
#pragma unroll
  for (int c = 0; c < 8; ++c) qf[c] = *(const bf16x8*)&qbase[c * 16];

  const char* kgbase = (const char*)(kext + (size_t)bh * 1024 * 128);
  const char* vgbase = (const char*)(vT + (size_t)bh * 64 * 1024);

  f32x16 O[2] = {};
  float l_lane = 0.f;

  bf16x8 kreg[4], vreg[2];
#pragma unroll
  for (int c = 0; c < 4; ++c) {
    int u = c * 256 + t;
    kreg[c] = *(const bf16x8*)(kgbase + (size_t)(u >> 4) * 256 + (u & 15) * 16);
  }
#pragma unroll
  for (int c = 0; c < 2; ++c) {
    int u = c * 256 + t;
    vreg[c] = *(const bf16x8*)(vgbase + (size_t)(u >> 3) * 2048 + (u & 7) * 16);
  }
#pragma unroll
  for (int c = 0; c < 4; ++c) {
    int u = c * 256 + t, r = u >> 4, s = u & 15;
    *(bf16x8*)((char*)KtS[0] + (size_t)r * 256 + (s ^ ((r ^ (r >> 3)) & 7)) * 16) = kreg[c];
  }
#pragma unroll
  for (int c = 0; c < 2; ++c) {
    int u = c * 256 + t, r = u >> 3, s = u & 7;
    *(bf16x8*)((char*)VtS[0] + (size_t)r * 128 + (s ^ ((r ^ (r >> 3)) & 7)) * 16) = vreg[c];
  }
#pragma unroll
  for (int c = 0; c < 4; ++c) {
    int u = c * 256 + t;
    kreg[c] = *(const bf16x8*)(kgbase + 64 * 256 + (size_t)(u >> 4) * 256 + (u & 15) * 16);
  }
#pragma unroll
  for (int c = 0; c < 2; ++c) {
    int u = c * 256 + t;
    vreg[c] = *(const bf16x8*)(vgbase + 64 * 2 + (size_t)(u >> 3) * 2048 + (u & 7) * 16);
  }
  __syncthreads();

  int krow = wk * 32 + l31;
  int ksalt = (krow ^ (krow >> 3)) & 7;

  for (int it = 0; it < 16; ++it) {
    int cur = it & 1;
    const char* Kb = (const char*)(KtS[cur]);
    const char* Vb = (const char*)(VtS[cur]);

    f32x16 sa = {};
#pragma unroll
    for (int kh = 0; kh < 2; ++kh) {
      bf16x8 kfr[4];
#pragma unroll
      for (int kc = 0; kc < 4; ++kc) {
        int slot = ((kh * 4 + kc) * 2 + lh) ^ ksalt;
        kfr[kc] = *(const bf16x8*)(Kb + (size_t)krow * 256 + slot * 16);
      }
      __builtin_amdgcn_s_setprio(1);
#pragma unroll
      for (int kc = 0; kc < 4; ++kc)
        sa = __builtin_amdgcn_mfma_f32_32x32x16_bf16(kfr[kc], qf[kh * 4 + kc], sa, 0, 0, 0);
      __builtin_amdgcn_s_setprio(0);
    }

    float p[16];
#pragma unroll
    for (int i = 0; i < 16; ++i) {
      p[i] = __expf(sa[i]);
      l_lane += p[i];
    }
    unsigned wv[8], xv[8];
#pragma unroll
    for (int j = 0; j < 8; ++j) wv[j] = cvt_pk_bf16(p[2 * j], p[2 * j + 1]);
#pragma unroll
    for (int j = 0; j < 8; ++j) xv[j] = (unsigned)__shfl_xor((int)wv[j], 32, 64);
    int4 pa0i = lh ? (int4){(int)xv[2], (int)xv[3], (int)wv[2], (int)wv[3]}
                   : (int4){(int)wv[0], (int)wv[1], (int)xv[0], (int)xv[1]};
    int4 pa1i = lh ? (int4){(int)xv[6], (int)xv[7], (int)wv[6], (int)wv[7]}
                   : (int4){(int)wv[4], (int)wv[5], (int)xv[4], (int)xv[5]};
    bf16x8 pa[2] = {*(bf16x8*)&pa0i, *(bf16x8*)&pa1i};

#pragma unroll
    for (int dn = 0; dn < 2; ++dn) {
      int d = dn * 32 + l31;
      int dsalt = (d ^ (d >> 3)) & 7;
      bf16x8 vf[2];
#pragma unroll
      for (int kc = 0; kc < 2; ++kc) {
        int slot = (wk * 4 + kc * 2 + lh) ^ dsalt;
        vf[kc] = *(const bf16x8*)(Vb + (size_t)d * 128 + slot * 16);
      }
      __builtin_amdgcn_s_setprio(1);
#pragma unroll
      for (int kc = 0; kc < 2; ++kc)
        O[dn] = __builtin_amdgcn_mfma_f32_32x32x16_bf16(pa[kc], vf[kc], O[dn], 0, 0, 0);
      __builtin_amdgcn_s_setprio(0);
    }

    if (it < 15) {
      char* Kw = (char*)(KtS[cur ^ 1]);
      char* Vw = (char*)(VtS[cur ^ 1]);
#pragma unroll
      for (int c = 0; c < 4; ++c) {
        int u = c * 256 + t, r = u >> 4, s = u & 15;
        *(bf16x8*)(Kw + (size_t)r * 256 + (s ^ ((r ^ (r >> 3)) & 7)) * 16) = kreg[c];
      }
#pragma unroll
      for (int c = 0; c < 2; ++c) {
        int u = c * 256 + t, r = u >> 3, s = u & 7;
        *(bf16x8*)(Vw + (size_t)r * 128 + (s ^ ((r ^ (r >> 3)) & 7)) * 16) = vreg[c];
      }
      if (it < 14) {
        const char* kg = kgbase + (size_t)(it + 2) * 64 * 256;
#pragma unroll
        for (int c = 0; c < 4; ++c) {
          int u = c * 256 + t;
          kreg[c] = *(const bf16x8*)(kg + (size_t)(u >> 4) * 256 + (u & 15) * 16);
        }
        const char* vg = vgbase + (size_t)(it + 2) * 64 * 2;
#pragma unroll
        for (int c = 0; c < 2; ++c) {
          int u = c * 256 + t;
          vreg[c] = *(const bf16x8*)(vg + (size_t)(u >> 3) * 2048 + (u & 7) * 16);
        }
      }
    }
    __syncthreads();
  }

  l_lane += __shfl_xor(l_lane, 32, 64);
  if (lh == 0) Lsum[wk][wq][l31] = l_lane;
  float* scratch = (float*)KtS[0];
  if (wk == 1) {
#pragma unroll
    for (int i = 0; i < 16; ++i) {
      int qr = wq * 32 + ((i & 3) + 8 * (i >> 2) + 4 * lh);
      scratch[qr * 64 + l31] = O[0][i];
      scratch[qr * 64 + 32 + l31] = O[1][i];
    }
  }
  __syncthreads();
  if (wk == 0) {
#pragma unroll
    for (int i = 0; i < 16; ++i) {
      int cr = (i & 3) + 8 * (i >> 2) + 4 * lh;
      int qr = wq * 32 + cr;
      float inv = 1.0f / (Lsum[0][wq][cr] + Lsum[1][wq][cr]);
      float* op = out + ((size_t)b * 1024 + q0 + qr) * 512 + h * 64;
      op[l31] = (O[0][i] + scratch[qr * 64 + l31]) * inv;
      op[32 + l31] = (O[1][i] + scratch[qr * 64 + 32 + l31]) * inv;
    }
  }
}

extern "C" void kernel_launch(void* const* d_in, const int* in_sizes, int n_in,
                              void* d_out, int out_size, void* d_ws, size_t ws_size,
                              hipStream_t stream) {
  const float* x = (const float*)d_in[0];
  const float* W = (const float*)d_in[1];
  const float* bias = (const float*)d_in[2];
  float* out = (float*)d_out;

  UST* ws = (UST*)d_ws;
  UST* xbf  = ws;                       // 4096*512
  UST* WT   = xbf + 4096 * 512;         // 1536*512
  UST* qext = WT + 1536 * 512;          // 32*1024*128
  UST* kext = qext + 32 * 1024 * 128;   // 32*1024*128
  UST* vT   = kext + 32 * 1024 * 128;   // 32*64*1024

  k_convert_x<<<dim3(6144), dim3(256), 0, stream>>>(x, xbf, kext);
  k_transpose_W<<<dim3(24, 8), dim3(256), 0, stream>>>(W, WT);
  k_proj<<<dim3(32, 24), dim3(256), 0, stream>>>(xbf, WT, bias, qext, kext, vT);
  k_attn<<<dim3(512), dim3(256), 0, stream>>>(qext, kext, vT, out);
}

// Round 17
// 54.275 us; speedup vs baseline: 1.2883x; 1.0429x over previous
//
#include <hip/hip_runtime.h>

typedef unsigned short UST;
typedef __attribute__((ext_vector_type(8))) __bf16 bf16x8;
typedef __attribute__((ext_vector_type(4))) float f32x4;
typedef __attribute__((ext_vector_type(16))) float f32x16;

#define NB 4
#define NH 8
#define LSEQ 1024
#define DMODEL 512
#define DH 64

__device__ __forceinline__ UST f2bf(float f) {
  union { float f; unsigned u; } v; v.f = f;
  unsigned u = v.u;
  return (UST)((u + 0x7FFFu + ((u >> 16) & 1u)) >> 16);
}
__device__ __forceinline__ float bf2f(UST h) {
  union { unsigned u; float f; } v; v.u = ((unsigned)h) << 16;
  return v.f;
}
__device__ __forceinline__ unsigned cvt_pk_bf16(float lo, float hi) {
  unsigned r;
  asm volatile("v_cvt_pk_bf16_f32 %0, %1, %2" : "=v"(r) : "v"(lo), "v"(hi));
  return r;
}

// ---------------- kernel 1: fused setup ----------------
// blocks 0..2047:    x fp32 -> bf16 (verbatim R16 path)
// blocks 2048..6143: beta fill of kext cols 64..127 (verbatim R16 path)
// blocks 6144..6335: W transpose -> WT bf16 (verbatim R16 k_transpose_W, 24x8 tiles)
__global__ void k_setup(const float* __restrict__ x, UST* __restrict__ xbf,
                        UST* __restrict__ kext,
                        const float* __restrict__ W, UST* __restrict__ WT) {
  __shared__ float tile[64][65];
  int bid = blockIdx.x;
  if (bid < 2048) {
    int i = bid * 256 + threadIdx.x;   // 2097152/4 elements
    float4 v = ((const float4*)x)[i];
    ushort4 o;
    o.x = f2bf(v.x); o.y = f2bf(v.y); o.z = f2bf(v.z); o.w = f2bf(v.w);
    ((ushort4*)xbf)[i] = o;
  } else if (bid < 6144) {
    int gid = (bid - 2048) * 256 + threadIdx.x;  // 32*1024*32
    int j = gid & 31;
    int l = (gid >> 5) & 1023;
    int bh = gid >> 15;
    float dd = exp2f((float)(-2 * j) * 0.20762050593046f);
    float ang = (float)l * dd;
    float s = __sinf(ang), c = __cosf(ang);
    UST* kp = kext + ((size_t)bh * 1024 + l) * 128;
    kp[64 + j] = f2bf(c);
    kp[96 + j] = f2bf(s);
  } else {
    int tid = bid - 6144;               // 0..191 = 24 x 8 tiles
    int n0 = (tid % 24) * 64;           // over 1536
    int k0 = (tid / 24) * 64;           // over 512
    int tx = threadIdx.x & 63, ty = threadIdx.x >> 6;  // ty 0..3
#pragma unroll
    for (int i = 0; i < 16; ++i) {
      int k = ty + i * 4;
      tile[k][tx] = W[(size_t)(k0 + k) * 1536 + n0 + tx];
    }
    __syncthreads();
#pragma unroll
    for (int i = 0; i < 16; ++i) {
      int n = ty + i * 4;
      WT[(size_t)(n0 + n) * 512 + k0 + tx] = f2bf(tile[tx][n]);
    }
  }
}

// ---------------- kernel 3: projection GEMM + scatter + fused alpha ----------------
// R16-verified compute/scatter/alpha, with the R15-verified dbuf skeleton:
// AtS[2]/BtS[2] (48KB -> 3 blocks/CU at grid 768), ONE barrier per K-step.
// Iter n: {compute buf[n&1]; ds_write tile n+1 -> buf[(n+1)&1]; issue loads n+2;
// barrier}. Register profile unchanged (areg[4], breg[2]).
__global__ __launch_bounds__(256) void k_proj(
    const UST* __restrict__ xbf, const UST* __restrict__ WT, const float* __restrict__ bias,
    UST* __restrict__ qext, UST* __restrict__ kext, UST* __restrict__ vT) {
  int m0 = blockIdx.x * 128;  // token tile
  int n0 = blockIdx.y * 64;   // out-col tile
  int t = threadIdx.x;
  int lane = t & 63, w = t >> 6;
  int wr = w >> 1, wc = w & 1;
  int g = lane >> 4, c16 = lane & 15;

  __shared__ UST AtS[2][128 * 64];  // 2 x 16KB; (row, slot s) holds (row, s^(row&7)) [16B units]
  __shared__ UST BtS[2][64 * 64];   // 2 x 8KB; same swizzle

  const char* Ag = (const char*)(xbf + (size_t)m0 * 512);  // row stride 1024B
  const char* Bg = (const char*)(WT + (size_t)n0 * 512);   // row stride 1024B

  bf16x8 areg[4], breg[2];
  // ---- prologue: tile 0 -> regs -> buf0; issue tile 1 loads; barrier
#pragma unroll
  for (int c = 0; c < 4; ++c) {
    int u = c * 256 + t, r = u >> 3, s = u & 7;
    areg[c] = *(const bf16x8*)(Ag + (size_t)r * 1024 + s * 16);
  }
#pragma unroll
  for (int c = 0; c < 2; ++c) {
    int u = c * 256 + t, r = u >> 3, s = u & 7;
    breg[c] = *(const bf16x8*)(Bg + (size_t)r * 1024 + s * 16);
  }
#pragma unroll
  for (int c = 0; c < 4; ++c) {
    int u = c * 256 + t, r = u >> 3, s = u & 7;
    *(bf16x8*)((char*)AtS[0] + (size_t)r * 128 + (s ^ (r & 7)) * 16) = areg[c];
  }
#pragma unroll
  for (int c = 0; c < 2; ++c) {
    int u = c * 256 + t, r = u >> 3, s = u & 7;
    *(bf16x8*)((char*)BtS[0] + (size_t)r * 128 + (s ^ (r & 7)) * 16) = breg[c];
  }
#pragma unroll
  for (int c = 0; c < 4; ++c) {
    int u = c * 256 + t, r = u >> 3, s = u & 7;
    areg[c] = *(const bf16x8*)(Ag + (size_t)r * 1024 + 128 + s * 16);
  }
#pragma unroll
  for (int c = 0; c < 2; ++c) {
    int u = c * 256 + t, r = u >> 3, s = u & 7;
    breg[c] = *(const bf16x8*)(Bg + (size_t)r * 1024 + 128 + s * 16);
  }
  __syncthreads();

  f32x4 acc[4][2] = {};
  for (int it = 0; it < 8; ++it) {
    int cur = it & 1;
    const char* Ab = (const char*)(AtS[cur]);
    const char* Bb = (const char*)(BtS[cur]);

#pragma unroll
    for (int kf = 0; kf < 2; ++kf) {
      bf16x8 af[4], bfr[2];
#pragma unroll
      for (int rf = 0; rf < 4; ++rf) {
        int r = wr * 64 + rf * 16 + c16;
        int s = (kf * 4 + g) ^ (r & 7);
        af[rf] = *(const bf16x8*)(Ab + (size_t)r * 128 + s * 16);
      }
#pragma unroll
      for (int cf = 0; cf < 2; ++cf) {
        int r = wc * 32 + cf * 16 + c16;
        int s = (kf * 4 + g) ^ (r & 7);
        bfr[cf] = *(const bf16x8*)(Bb + (size_t)r * 128 + s * 16);
      }
      __builtin_amdgcn_s_setprio(1);
#pragma unroll
      for (int rf = 0; rf < 4; ++rf)
#pragma unroll
        for (int cf = 0; cf < 2; ++cf)
          acc[rf][cf] = __builtin_amdgcn_mfma_f32_16x16x32_bf16(af[rf], bfr[cf], acc[rf][cf], 0, 0, 0);
      __builtin_amdgcn_s_setprio(0);
    }

    // ---- stage tile it+1 into buf[cur^1]; issue loads for tile it+2
    if (it < 7) {
      char* Aw = (char*)(AtS[cur ^ 1]);
      char* Bw = (char*)(BtS[cur ^ 1]);
#pragma unroll
      for (int c = 0; c < 4; ++c) {
        int u = c * 256 + t, r = u >> 3, s = u & 7;
        *(bf16x8*)(Aw + (size_t)r * 128 + (s ^ (r & 7)) * 16) = areg[c];
      }
#pragma unroll
      for (int c = 0; c < 2; ++c) {
        int u = c * 256 + t, r = u >> 3, s = u & 7;
        *(bf16x8*)(Bw + (size_t)r * 128 + (s ^ (r & 7)) * 16) = breg[c];
      }
      if (it < 6) {
        size_t cb = (size_t)(it + 2) * 128;
#pragma unroll
        for (int c = 0; c < 4; ++c) {
          int u = c * 256 + t, r = u >> 3, s = u & 7;
          areg[c] = *(const bf16x8*)(Ag + (size_t)r * 1024 + cb + s * 16);
        }
#pragma unroll
        for (int c = 0; c < 2; ++c) {
          int u = c * 256 + t, r = u >> 3, s = u & 7;
          breg[c] = *(const bf16x8*)(Bg + (size_t)r * 1024 + cb + s * 16);
        }
      }
    }
    __syncthreads();
  }

  bool doalpha = (blockIdx.y % 3 == 0);   // block-uniform
  UST* stash = AtS[0];                    // free after final barrier (last buf0 read was it=6)

#pragma unroll
  for (int rf = 0; rf < 4; ++rf) {
#pragma unroll
    for (int cf = 0; cf < 2; ++cf) {
      int c = n0 + wc * 32 + cf * 16 + c16;
      int h = c / 192, rem = c % 192;
      float bv = bias[c];
#pragma unroll
      for (int r = 0; r < 4; ++r) {
        int row = m0 + wr * 64 + rf * 16 + g * 4 + r;
        int bidx = row >> 10, ltok = row & 1023;
        int bh = bidx * 8 + h;
        float val = acc[rf][cf][r] + bv;
        if (rem < 64) {
          UST qv = f2bf(val * 0.125f);
          qext[((size_t)bh * 1024 + ltok) * 128 + rem] = qv;
          if (doalpha)  // stash scaled q for alpha (rem==local col for y%3==0)
            stash[(size_t)(row - m0) * 64 + rem] = qv;
        } else if (rem < 128)
          kext[((size_t)bh * 1024 + ltok) * 128 + (rem - 64)] = f2bf(val);
        else
          vT[((size_t)bh * 64 + (rem - 128)) * 1024 + ltok] = f2bf(val);
      }
    }
  }

  if (doalpha) {
    __syncthreads();                      // stash complete
    int hh = blockIdx.y / 3;              // head
    int rr = t >> 1;                      // local row 0..127
    int row = m0 + rr;
    int bidx = row >> 10, ltok = row & 1023;
    int bh = bidx * 8 + hh;
    UST* qp = qext + ((size_t)bh * 1024 + ltok) * 128;
#pragma unroll
    for (int i = 0; i < 16; ++i) {
      int j = (t & 1) * 16 + i;
      float dd = exp2f((float)(-2 * j) * 0.20762050593046f);
      float ang = (float)ltok * dd;
      float s = __sinf(ang), c = __cosf(ang);
      float qs = bf2f(stash[(size_t)rr * 64 + j]);
      float qc = bf2f(stash[(size_t)rr * 64 + 32 + j]);
      qp[64 + j] = f2bf(qs * s + qc * c);
      qp[96 + j] = f2bf(qc * s - qs * c);
    }
  }
}

// ---------------- kernel 5: fused flash attention (R15/R16-verified, unchanged) ------
__global__ __launch_bounds__(256) void k_attn(
    const UST* __restrict__ qext, const UST* __restrict__ kext,
    const UST* __restrict__ vT, float* __restrict__ out) {
  int blk = ((blockIdx.x & 7) << 6) | (blockIdx.x >> 3);  // XCD-contiguous bh ranges
  int qt = blk & 15, bh = blk >> 4;
  int b = bh >> 3, h = bh & 7;
  int q0 = qt * 64;
  int t = threadIdx.x;
  int lane = t & 63, w = t >> 6;
  int l31 = lane & 31, lh = lane >> 5;
  int wq = w >> 1, wk = w & 1;

  __shared__ UST KtS[2][64 * 128];   // 2 x 16KB
  __shared__ UST VtS[2][64 * 64];    // 2 x 8KB
  __shared__ float Lsum[2][2][32];   // [wk][wq][row]

  const UST* qbase = qext + ((size_t)bh * 1024 + q0 + wq * 32 + l31) * 128 + lh * 8;
  bf16x8 qf[8];
#pragma unroll
  for (int c = 0; c < 8; ++c) qf[c] = *(const bf16x8*)&qbase[c * 16];

  const char* kgbase = (const char*)(kext + (size_t)bh * 1024 * 128);
  const char* vgbase = (const char*)(vT + (size_t)bh * 64 * 1024);

  f32x16 O[2] = {};
  float l_lane = 0.f;

  bf16x8 kreg[4], vreg[2];
#pragma unroll
  for (int c = 0; c < 4; ++c) {
    int u = c * 256 + t;
    kreg[c] = *(const bf16x8*)(kgbase + (size_t)(u >> 4) * 256 + (u & 15) * 16);
  }
#pragma unroll
  for (int c = 0; c < 2; ++c) {
    int u = c * 256 + t;
    vreg[c] = *(const bf16x8*)(vgbase + (size_t)(u >> 3) * 2048 + (u & 7) * 16);
  }
#pragma unroll
  for (int c = 0; c < 4; ++c) {
    int u = c * 256 + t, r = u >> 4, s = u & 15;
    *(bf16x8*)((char*)KtS[0] + (size_t)r * 256 + (s ^ ((r ^ (r >> 3)) & 7)) * 16) = kreg[c];
  }
#pragma unroll
  for (int c = 0; c < 2; ++c) {
    int u = c * 256 + t, r = u >> 3, s = u & 7;
    *(bf16x8*)((char*)VtS[0] + (size_t)r * 128 + (s ^ ((r ^ (r >> 3)) & 7)) * 16) = vreg[c];
  }
#pragma unroll
  for (int c = 0; c < 4; ++c) {
    int u = c * 256 + t;
    kreg[c] = *(const bf16x8*)(kgbase + 64 * 256 + (size_t)(u >> 4) * 256 + (u & 15) * 16);
  }
#pragma unroll
  for (int c = 0; c < 2; ++c) {
    int u = c * 256 + t;
    vreg[c] = *(const bf16x8*)(vgbase + 64 * 2 + (size_t)(u >> 3) * 2048 + (u & 7) * 16);
  }
  __syncthreads();

  int krow = wk * 32 + l31;
  int ksalt = (krow ^ (krow >> 3)) & 7;

  for (int it = 0; it < 16; ++it) {
    int cur = it & 1;
    const char* Kb = (const char*)(KtS[cur]);
    const char* Vb = (const char*)(VtS[cur]);

    f32x16 sa = {};
#pragma unroll
    for (int kh = 0; kh < 2; ++kh) {
      bf16x8 kfr[4];
#pragma unroll
      for (int kc = 0; kc < 4; ++kc) {
        int slot = ((kh * 4 + kc) * 2 + lh) ^ ksalt;
        kfr[kc] = *(const bf16x8*)(Kb + (size_t)krow * 256 + slot * 16);
      }
      __builtin_amdgcn_s_setprio(1);
#pragma unroll
      for (int kc = 0; kc < 4; ++kc)
        sa = __builtin_amdgcn_mfma_f32_32x32x16_bf16(kfr[kc], qf[kh * 4 + kc], sa, 0, 0, 0);
      __builtin_amdgcn_s_setprio(0);
    }

    float p[16];
#pragma unroll
    for (int i = 0; i < 16; ++i) {
      p[i] = __expf(sa[i]);
      l_lane += p[i];
    }
    unsigned wv[8], xv[8];
#pragma unroll
    for (int j = 0; j < 8; ++j) wv[j] = cvt_pk_bf16(p[2 * j], p[2 * j + 1]);
#pragma unroll
    for (int j = 0; j < 8; ++j) xv[j] = (unsigned)__shfl_xor((int)wv[j], 32, 64);
    int4 pa0i = lh ? (int4){(int)xv[2], (int)xv[3], (int)wv[2], (int)wv[3]}
                   : (int4){(int)wv[0], (int)wv[1], (int)xv[0], (int)xv[1]};
    int4 pa1i = lh ? (int4){(int)xv[6], (int)xv[7], (int)wv[6], (int)wv[7]}
                   : (int4){(int)wv[4], (int)wv[5], (int)xv[4], (int)xv[5]};
    bf16x8 pa[2] = {*(bf16x8*)&pa0i, *(bf16x8*)&pa1i};

#pragma unroll
    for (int dn = 0; dn < 2; ++dn) {
      int d = dn * 32 + l31;
      int dsalt = (d ^ (d >> 3)) & 7;
      bf16x8 vf[2];
#pragma unroll
      for (int kc = 0; kc < 2; ++kc) {
        int slot = (wk * 4 + kc * 2 + lh) ^ dsalt;
        vf[kc] = *(const bf16x8*)(Vb + (size_t)d * 128 + slot * 16);
      }
      __builtin_amdgcn_s_setprio(1);
#pragma unroll
      for (int kc = 0; kc < 2; ++kc)
        O[dn] = __builtin_amdgcn_mfma_f32_32x32x16_bf16(pa[kc], vf[kc], O[dn], 0, 0, 0);
      __builtin_amdgcn_s_setprio(0);
    }

    if (it < 15) {
      char* Kw = (char*)(KtS[cur ^ 1]);
      char* Vw = (char*)(VtS[cur ^ 1]);
#pragma unroll
      for (int c = 0; c < 4; ++c) {
        int u = c * 256 + t, r = u >> 4, s = u & 15;
        *(bf16x8*)(Kw + (size_t)r * 256 + (s ^ ((r ^ (r >> 3)) & 7)) * 16) = kreg[c];
      }
#pragma unroll
      for (int c = 0; c < 2; ++c) {
        int u = c * 256 + t, r = u >> 3, s = u & 7;
        *(bf16x8*)(Vw + (size_t)r * 128 + (s ^ ((r ^ (r >> 3)) & 7)) * 16) = vreg[c];
      }
      if (it < 14) {
        const char* kg = kgbase + (size_t)(it + 2) * 64 * 256;
#pragma unroll
        for (int c = 0; c < 4; ++c) {
          int u = c * 256 + t;
          kreg[c] = *(const bf16x8*)(kg + (size_t)(u >> 4) * 256 + (u & 15) * 16);
        }
        const char* vg = vgbase + (size_t)(it + 2) * 64 * 2;
#pragma unroll
        for (int c = 0; c < 2; ++c) {
          int u = c * 256 + t;
          vreg[c] = *(const bf16x8*)(vg + (size_t)(u >> 3) * 2048 + (u & 7) * 16);
        }
      }
    }
    __syncthreads();
  }

  l_lane += __shfl_xor(l_lane, 32, 64);
  if (lh == 0) Lsum[wk][wq][l31] = l_lane;
  float* scratch = (float*)KtS[0];
  if (wk == 1) {
#pragma unroll
    for (int i = 0; i < 16; ++i) {
      int qr = wq * 32 + ((i & 3) + 8 * (i >> 2) + 4 * lh);
      scratch[qr * 64 + l31] = O[0][i];
      scratch[qr * 64 + 32 + l31] = O[1][i];
    }
  }
  __syncthreads();
  if (wk == 0) {
#pragma unroll
    for (int i = 0; i < 16; ++i) {
      int cr = (i & 3) + 8 * (i >> 2) + 4 * lh;
      int qr = wq * 32 + cr;
      float inv = 1.0f / (Lsum[0][wq][cr] + Lsum[1][wq][cr]);
      float* op = out + ((size_t)b * 1024 + q0 + qr) * 512 + h * 64;
      op[l31] = (O[0][i] + scratch[qr * 64 + l31]) * inv;
      op[32 + l31] = (O[1][i] + scratch[qr * 64 + 32 + l31]) * inv;
    }
  }
}

extern "C" void kernel_launch(void* const* d_in, const int* in_sizes, int n_in,
                              void* d_out, int out_size, void* d_ws, size_t ws_size,
                              hipStream_t stream) {
  const float* x = (const float*)d_in[0];
  const float* W = (const float*)d_in[1];
  const float* bias = (const float*)d_in[2];
  float* out = (float*)d_out;

  UST* ws = (UST*)d_ws;
  UST* xbf  = ws;                       // 4096*512
  UST* WT   = xbf + 4096 * 512;         // 1536*512
  UST* qext = WT + 1536 * 512;          // 32*1024*128
  UST* kext = qext + 32 * 1024 * 128;   // 32*1024*128
  UST* vT   = kext + 32 * 1024 * 128;   // 32*64*1024

  k_setup<<<dim3(6336), dim3(256), 0, stream>>>(x, xbf, kext, W, WT);
  k_proj<<<dim3(32, 24), dim3(256), 0, stream>>>(xbf, WT, bias, qext, kext, vT);
  k_attn<<<dim3(512), dim3(256), 0, stream>>>(qext, kext, vT, out);
}